// Round 1
// 522.142 us; speedup vs baseline: 1.0871x; 1.0871x over previous
//
#include <hip/hip_runtime.h>

// ---------------------------------------------------------------------------
// SelfAttentionDecoder: out = (softmax(mask((qWq^T+bq)(xWk^T+bk)^T/8)) (xWv^T+bv)) Wo^T + bo
// B=16, N1=N2=1024, D=1024, H=16, DH=64.
// Round 5: attn rewrite — double-buffered global_load_lds(16B) K/V staging
// (XOR-swizzled source, linear LDS dest, same pattern as gemm_lds), one
// barrier per chunk, mask words direct-to-register, exp2-folded scale
// (Q-GEMM scale = 0.125*log2e so softmax is a bare v_exp_f32).
// ---------------------------------------------------------------------------

typedef float f32x4 __attribute__((ext_vector_type(4)));
typedef __bf16 bf16x8 __attribute__((ext_vector_type(8)));

// 0.125 * log2(e): QK^T scores arrive pre-scaled for exp2-based softmax.
#define QSCALE 0.18033688f

__device__ __forceinline__ unsigned short f2bf(float f) {
    unsigned u = __builtin_bit_cast(unsigned, f);
    unsigned r = u + 0x7fffu + ((u >> 16) & 1u);   // RNE
    return (unsigned short)(r >> 16);
}
__device__ __forceinline__ unsigned pk2(float a, float b) {
    return (unsigned)f2bf(a) | ((unsigned)f2bf(b) << 16);
}

// ---------------------------------------------------------------------------
// fp32 -> bf16 converters.
// ---------------------------------------------------------------------------
__global__ __launch_bounds__(256) void cvt_bf16(const float* __restrict__ src,
                                                unsigned short* __restrict__ dst,
                                                int n8) {
    const int idx = blockIdx.x * 256 + threadIdx.x;
    if (idx >= n8) return;
    float4 a = ((const float4*)src)[idx * 2];
    float4 b = ((const float4*)src)[idx * 2 + 1];
    uint4 u;
    u.x = pk2(a.x, a.y); u.y = pk2(a.z, a.w);
    u.z = pk2(b.x, b.y); u.w = pk2(b.z, b.w);
    ((uint4*)dst)[idx] = u;
}

__global__ __launch_bounds__(256) void cvt_w4(const float* __restrict__ W0,
                                              const float* __restrict__ W1,
                                              const float* __restrict__ W2,
                                              const float* __restrict__ W3,
                                              unsigned short* __restrict__ o0,
                                              unsigned short* __restrict__ o1,
                                              unsigned short* __restrict__ o2,
                                              unsigned short* __restrict__ o3) {
    const float* s = (blockIdx.y == 0) ? W0 : (blockIdx.y == 1) ? W1
                   : (blockIdx.y == 2) ? W2 : W3;
    unsigned short* d = (blockIdx.y == 0) ? o0 : (blockIdx.y == 1) ? o1
                      : (blockIdx.y == 2) ? o2 : o3;
    const int idx = blockIdx.x * 256 + threadIdx.x;   // 131072 chunks of 8
    float4 a = ((const float4*)s)[idx * 2];
    float4 b = ((const float4*)s)[idx * 2 + 1];
    uint4 u;
    u.x = pk2(a.x, a.y); u.y = pk2(a.z, a.w);
    u.z = pk2(b.x, b.y); u.w = pk2(b.z, b.w);
    ((uint4*)d)[idx] = u;
}

// ---------------------------------------------------------------------------
// GEMM (m97-class): C[M,N] = (A[M,K] @ W[N,K]^T + bias)*scale, bf16 in.
// M=16384 N=1024 K=1024. 128x128 tile, BK=64, 256 thr (4 waves, 2x2 of 64x64).
// Staging: 8x global_load_lds(16B)/thread/iter into unpadded 128x64 tiles;
// XOR swizzle on the GLOBAL source col-chunk (csrc = cpos ^ (row&7)) so the
// LDS image has chunk c of row r at position c^(r&7); frag reads then spread
// 64 lanes over all 8 chunk positions (8 dwords/bank = b128 floor).
// OUTM: 0 = bf16 row-major; 1 = fp32 row-major; 2 = bf16 V^T [b][h][dh][n2].
// ---------------------------------------------------------------------------
template <int OUTM>
__global__ __launch_bounds__(256) void gemm_lds(const unsigned short* __restrict__ A,
                                                const unsigned short* __restrict__ W,
                                                const float* __restrict__ bias,
                                                void* __restrict__ Cp,
                                                float scale) {
    constexpr int N = 1024, K = 1024;
    __shared__ unsigned short As[128 * 64];
    __shared__ unsigned short Bs[128 * 64];

    const int t    = threadIdx.x;
    const int wave = t >> 6;
    const int lane = t & 63;
    const int n0   = blockIdx.x * 128;
    const int m0   = blockIdx.y * 128;
    const int wr   = (wave >> 1) * 64;
    const int wc   = (wave & 1) * 64;
    const int lm   = lane & 15;
    const int quad = lane >> 4;

    // staging: inst i covers LDS slots [(wave*4+i)*64 .. +64); slot s -> row
    // r=s>>3, chunk-pos p=s&7, source chunk csrc=p^(r&7).
    int aoff[4], boff[4];
#pragma unroll
    for (int i = 0; i < 4; i++) {
        const int slot = wave * 256 + i * 64 + lane;
        const int r = slot >> 3;
        const int csrc = (slot & 7) ^ (r & 7);
        aoff[i] = (m0 + r) * K + csrc * 8;
        boff[i] = (n0 + r) * K + csrc * 8;
    }

    f32x4 acc[4][4] = {};

    for (int k0 = 0; k0 < K; k0 += 64) {
#pragma unroll
        for (int i = 0; i < 4; i++) {
            __builtin_amdgcn_global_load_lds(
                (const __attribute__((address_space(1))) unsigned int*)(A + aoff[i] + k0),
                (__attribute__((address_space(3))) unsigned int*)((char*)As + wave * 4096 + i * 1024),
                16, 0, 0);
            __builtin_amdgcn_global_load_lds(
                (const __attribute__((address_space(1))) unsigned int*)(W + boff[i] + k0),
                (__attribute__((address_space(3))) unsigned int*)((char*)Bs + wave * 4096 + i * 1024),
                16, 0, 0);
        }
        __syncthreads();

        bf16x8 af[2][4], bfr[2][4];
#pragma unroll
        for (int ks = 0; ks < 2; ks++)
#pragma unroll
            for (int i = 0; i < 4; i++) {
                const int pos = ((ks * 4 + quad) ^ (lm & 7)) * 16;
                af[ks][i]  = *(const bf16x8*)((const char*)As + (wr + i * 16 + lm) * 128 + pos);
                bfr[ks][i] = *(const bf16x8*)((const char*)Bs + (wc + i * 16 + lm) * 128 + pos);
            }
#pragma unroll
        for (int ks = 0; ks < 2; ks++)
#pragma unroll
            for (int i = 0; i < 4; i++)
#pragma unroll
                for (int j = 0; j < 4; j++)
                    acc[i][j] = __builtin_amdgcn_mfma_f32_16x16x32_bf16(af[ks][i], bfr[ks][j],
                                                                        acc[i][j], 0, 0, 0);
        __syncthreads();
    }

    // ---- epilogue ----
#pragma unroll
    for (int i = 0; i < 4; i++) {
        const int row = m0 + wr + i * 16 + quad * 4;
#pragma unroll
        for (int j = 0; j < 4; j++) {
            const int col = n0 + wc + j * 16 + lm;
            const float bb = bias[col];
            if constexpr (OUTM == 2) {
                const int bi = row >> 10, n2 = row & 1023;
                const int hh = col >> 6, dh = col & 63;
                uint2 pkd;
                pkd.x = pk2((acc[i][j][0] + bb) * scale, (acc[i][j][1] + bb) * scale);
                pkd.y = pk2((acc[i][j][2] + bb) * scale, (acc[i][j][3] + bb) * scale);
                *(uint2*)&((unsigned short*)Cp)[((size_t)((bi * 16 + hh) * 64 + dh) << 10) + n2] = pkd;
            } else {
#pragma unroll
                for (int rr = 0; rr < 4; rr++) {
                    const float v = (acc[i][j][rr] + bb) * scale;
                    if constexpr (OUTM == 0)
                        ((unsigned short*)Cp)[(size_t)(row + rr) * N + col] = f2bf(v);
                    else
                        ((float*)Cp)[(size_t)(row + rr) * N + col] = v;
                }
            }
        }
    }
}

// ---------------------------------------------------------------------------
// Fallback GEMM (fp32 inputs, conversion in staging) — minimal-ws path only.
// ---------------------------------------------------------------------------
template <bool A_BF16, int OUTM>
__global__ __launch_bounds__(256) void gemm_bt(const void* __restrict__ Ap,
                                               const float* __restrict__ Wp,
                                               const float* __restrict__ bias,
                                               void* __restrict__ Cp,
                                               float scale) {
    constexpr int N = 1024, K = 1024;
    __shared__ unsigned short As[128 * 40];
    __shared__ unsigned short Bs[128 * 40];

    const int t    = threadIdx.x;
    const int n0   = blockIdx.x * 128;
    const int m0   = blockIdx.y * 128;
    const int wave = t >> 6;
    const int lane = t & 63;
    const int wr   = (wave >> 1) * 64;
    const int wc   = (wave & 1) * 64;
    const int lm   = lane & 15;
    const int quad = lane >> 4;
    const int kfr  = quad * 8;
    const int srow  = t >> 1;
    const int shalf = (t & 1) * 16;

    f32x4 acc[4][4] = {};

    for (int k0 = 0; k0 < K; k0 += 32) {
        {
            unsigned short* dst = &As[srow * 40 + shalf];
            if constexpr (A_BF16) {
                const unsigned short* pa =
                    (const unsigned short*)Ap + (size_t)(m0 + srow) * K + k0 + shalf;
                *(uint4*)dst       = *(const uint4*)pa;
                *(uint4*)(dst + 8) = *(const uint4*)(pa + 8);
            } else {
                const float* pa = (const float*)Ap + (size_t)(m0 + srow) * K + k0 + shalf;
                float4 f0 = *(const float4*)(pa + 0);
                float4 f1 = *(const float4*)(pa + 4);
                float4 f2 = *(const float4*)(pa + 8);
                float4 f3 = *(const float4*)(pa + 12);
                uint4 u0, u1;
                u0.x = pk2(f0.x, f0.y); u0.y = pk2(f0.z, f0.w);
                u0.z = pk2(f1.x, f1.y); u0.w = pk2(f1.z, f1.w);
                u1.x = pk2(f2.x, f2.y); u1.y = pk2(f2.z, f2.w);
                u1.z = pk2(f3.x, f3.y); u1.w = pk2(f3.z, f3.w);
                *(uint4*)dst       = u0;
                *(uint4*)(dst + 8) = u1;
            }
        }
        {
            const float* pb = Wp + (size_t)(n0 + srow) * K + k0 + shalf;
            float4 f0 = *(const float4*)(pb + 0);
            float4 f1 = *(const float4*)(pb + 4);
            float4 f2 = *(const float4*)(pb + 8);
            float4 f3 = *(const float4*)(pb + 12);
            uint4 u0, u1;
            u0.x = pk2(f0.x, f0.y); u0.y = pk2(f0.z, f0.w);
            u0.z = pk2(f1.x, f1.y); u0.w = pk2(f1.z, f1.w);
            u1.x = pk2(f2.x, f2.y); u1.y = pk2(f2.z, f2.w);
            u1.z = pk2(f3.x, f3.y); u1.w = pk2(f3.z, f3.w);
            unsigned short* dst = &Bs[srow * 40 + shalf];
            *(uint4*)dst       = u0;
            *(uint4*)(dst + 8) = u1;
        }
        __syncthreads();

        bf16x8 af[4], bfr[4];
#pragma unroll
        for (int i = 0; i < 4; i++)
            af[i] = *reinterpret_cast<const bf16x8*>(&As[(wr + i * 16 + lm) * 40 + kfr]);
#pragma unroll
        for (int j = 0; j < 4; j++)
            bfr[j] = *reinterpret_cast<const bf16x8*>(&Bs[(wc + j * 16 + lm) * 40 + kfr]);
#pragma unroll
        for (int i = 0; i < 4; i++)
#pragma unroll
            for (int j = 0; j < 4; j++)
                acc[i][j] = __builtin_amdgcn_mfma_f32_16x16x32_bf16(af[i], bfr[j],
                                                                    acc[i][j], 0, 0, 0);
        __syncthreads();
    }

#pragma unroll
    for (int i = 0; i < 4; i++) {
        const int row = m0 + wr + i * 16 + quad * 4;
#pragma unroll
        for (int j = 0; j < 4; j++) {
            const int col = n0 + wc + j * 16 + lm;
            const float bb = bias[col];
#pragma unroll
            for (int rr = 0; rr < 4; rr++) {
                const float v = (acc[i][j][rr] + bb) * scale;
                const int m = row + rr;
                if constexpr (OUTM == 0) {
                    ((unsigned short*)Cp)[(size_t)m * N + col] = f2bf(v);
                } else if constexpr (OUTM == 1) {
                    ((float*)Cp)[(size_t)m * N + col] = v;
                } else {
                    const int bi = m >> 10, n2 = m & 1023;
                    const int hh = col >> 6, dh = col & 63;
                    ((unsigned short*)Cp)[((size_t)((bi * 16 + hh) * 64 + dh) << 10) + n2] =
                        f2bf(v);
                }
            }
        }
    }
}

// ---------------------------------------------------------------------------
// Pack adj (int32 0/1, [1024][1024]) into bitmask [1024][32] words.
// ---------------------------------------------------------------------------
__global__ __launch_bounds__(256) void pack_adj(const int* __restrict__ adj,
                                                unsigned* __restrict__ adjm) {
    const int idx = blockIdx.x * 256 + threadIdx.x;  // 0..32767
    const int* src = adj + (size_t)idx * 32;
    unsigned w = 0;
#pragma unroll
    for (int i = 0; i < 32; i++) w |= (src[i] != 0 ? 1u : 0u) << i;
    adjm[idx] = w;
}

// ---------------------------------------------------------------------------
// MFMA flash attention, no-max softmax. Block = (128 q, h, b), 4 waves.
// R5 structure per 64-kv chunk:
//   mask uint2 loads (oldest in vmem queue -> their wait leaves staging alive)
//   -> issue global_load_lds(16B) K/V stage of chunk c+1 into buf^1
//   -> ds_read frags of chunk c (XOR-swizzled image, b128 floor)
//   -> QK^T MFMA, bit-mask + v_exp_f32 (exp2; scale pre-folded), P round trip
//      through per-wave Ps (no barrier needed), PV + l MFMA
//   -> one __syncthreads() (its vmcnt(0) drain is the stage completion wait).
// LDS: 2x8KB K + 2x8KB V + 9KB Ps = 41KB -> 3 blocks/CU.
// ---------------------------------------------------------------------------
__global__ __launch_bounds__(256, 3) void attn_kernel(const unsigned short* __restrict__ Q,
                                                      const unsigned short* __restrict__ K,
                                                      const unsigned short* __restrict__ Vt,
                                                      const unsigned* __restrict__ adjm,
                                                      unsigned short* __restrict__ O) {
    __shared__ unsigned short Kbuf[2][4096];   // [row=kv 0..63][pos 0..7 of 8 ushorts]
    __shared__ unsigned short Vbuf[2][4096];   // [row=dh 0..63][pos]
    __shared__ unsigned short Ps[4][16][72];   // per-wave P round-trip

    const int t    = threadIdx.x;
    const int wave = t >> 6;
    const int lane = t & 63;
    const int lml  = lane & 15;
    const int quad = lane >> 4;
    const int q0   = blockIdx.x * 128;
    const int h    = blockIdx.y;
    const int b    = blockIdx.z;

    // staging precompute: slot s covers buf bytes [s*16, s*16+16); row r=s>>3,
    // stored pos p=s&7, source chunk csrc=p^(r&7) (image: chunk c at c^(r&7)).
    int    ldofs[2];
    size_t kofs[2], vofs[2];
#pragma unroll
    for (int i = 0; i < 2; i++) {
        const int slot = i * 256 + t;
        const int r    = slot >> 3;
        const int cs   = (slot & 7) ^ (r & 7);
        ldofs[i] = slot * 16;
        kofs[i]  = (size_t)(b * 1024 + r) * 1024 + h * 64 + cs * 8;   // + j0*1024
        vofs[i]  = ((size_t)((b * 16 + h) * 64 + r) << 10) + cs * 8;  // + j0
    }

    bf16x8 aq[2][2];
#pragma unroll
    for (int g = 0; g < 2; g++) {
        const unsigned short* qp =
            Q + ((size_t)(b * 1024 + q0 + wave * 32 + g * 16 + lml) * 1024 + h * 64 + quad * 8);
        aq[g][0] = __builtin_bit_cast(bf16x8, *(const uint4*)qp);
        aq[g][1] = __builtin_bit_cast(bf16x8, *(const uint4*)(qp + 32));
    }

    bf16x8 bones;
    {
        const unsigned short o1 = (lml == 0) ? (unsigned short)0x3F80 : (unsigned short)0;
        const unsigned oo = (unsigned)o1 | ((unsigned)o1 << 16);
        uint4 u; u.x = oo; u.y = oo; u.z = oo; u.w = oo;
        bones = __builtin_bit_cast(bf16x8, u);
    }

    f32x4 of[2][4] = {};
    f32x4 ol[2] = {};

    auto STAGE = [&](int bi, int c) {
        const size_t j0 = (size_t)c * 64;
#pragma unroll
        for (int i = 0; i < 2; i++) {
            __builtin_amdgcn_global_load_lds(
                (const __attribute__((address_space(1))) unsigned int*)(K + kofs[i] + j0 * 1024),
                (__attribute__((address_space(3))) unsigned int*)((char*)&Kbuf[bi][0] + ldofs[i]),
                16, 0, 0);
            __builtin_amdgcn_global_load_lds(
                (const __attribute__((address_space(1))) unsigned int*)(Vt + vofs[i] + j0),
                (__attribute__((address_space(3))) unsigned int*)((char*)&Vbuf[bi][0] + ldofs[i]),
                16, 0, 0);
        }
    };

    STAGE(0, 0);
    __syncthreads();   // vmcnt(0) drain: buf0 ready

    int bi = 0;
    for (int c = 0; c < 16; ++c) {
        // mask words for this chunk -> registers (issued before the stage so
        // the compiler's wait for them leaves the 4 gll loads in flight)
        uint2 mw[2][4];
#pragma unroll
        for (int g = 0; g < 2; g++)
#pragma unroll
            for (int rr = 0; rr < 4; rr++) {
                const int row = q0 + wave * 32 + g * 16 + quad * 4 + rr;
                mw[g][rr] = *(const uint2*)&adjm[(size_t)row * 32 + c * 2];
            }

        if (c < 15) STAGE(bi ^ 1, c + 1);

        bf16x8 bk[4][2], bv[4][2];
#pragma unroll
        for (int f = 0; f < 4; f++)
#pragma unroll
            for (int ks = 0; ks < 2; ks++) {
                const int row = f * 16 + lml;
                const int pos = ((ks * 4 + quad) ^ (lml & 7)) * 16;
                bk[f][ks] = *(const bf16x8*)((const char*)&Kbuf[bi][0] + row * 128 + pos);
                bv[f][ks] = *(const bf16x8*)((const char*)&Vbuf[bi][0] + row * 128 + pos);
            }

#pragma unroll
        for (int g = 0; g < 2; g++) {
            f32x4 sf[4] = {};
#pragma unroll
            for (int f = 0; f < 4; f++)
#pragma unroll
                for (int ks = 0; ks < 2; ks++)
                    sf[f] = __builtin_amdgcn_mfma_f32_16x16x32_bf16(aq[g][ks], bk[f][ks],
                                                                    sf[f], 0, 0, 0);

#pragma unroll
            for (int rr = 0; rr < 4; rr++) {
                const unsigned w0 = mw[g][rr].x, w1 = mw[g][rr].y;
#pragma unroll
                for (int f = 0; f < 4; f++) {
                    const unsigned w = (f < 2) ? w0 : w1;
                    const unsigned bit = (w >> ((f * 16 + lml) & 31)) & 1u;
                    // scores pre-scaled by log2e -> bare v_exp_f32 (=exp2)
                    const float p = bit ? __builtin_amdgcn_exp2f(sf[f][rr]) : 0.0f;
                    // truncating bf16 convert (bias cancels in O/l ratio)
                    Ps[wave][quad * 4 + rr][f * 16 + lml] =
                        (unsigned short)(__builtin_bit_cast(unsigned, p) >> 16);
                }
            }
            const bf16x8 ap0 = *reinterpret_cast<const bf16x8*>(&Ps[wave][lml][quad * 8]);
            const bf16x8 ap1 = *reinterpret_cast<const bf16x8*>(&Ps[wave][lml][32 + quad * 8]);

#pragma unroll
            for (int f = 0; f < 4; f++) {
                of[g][f] = __builtin_amdgcn_mfma_f32_16x16x32_bf16(ap0, bv[f][0], of[g][f], 0, 0, 0);
                of[g][f] = __builtin_amdgcn_mfma_f32_16x16x32_bf16(ap1, bv[f][1], of[g][f], 0, 0, 0);
            }
            ol[g] = __builtin_amdgcn_mfma_f32_16x16x32_bf16(ap0, bones, ol[g], 0, 0, 0);
            ol[g] = __builtin_amdgcn_mfma_f32_16x16x32_bf16(ap1, bones, ol[g], 0, 0, 0);
        }

        __syncthreads();   // drain: next buf staged + all waves done reading bi
        bi ^= 1;
    }

#pragma unroll
    for (int g = 0; g < 2; g++) {
        float inv[4];
#pragma unroll
        for (int rr = 0; rr < 4; rr++)
            inv[rr] = 1.0f / __shfl(ol[g][rr], lane & 48);
#pragma unroll
        for (int f = 0; f < 4; f++)
#pragma unroll
            for (int rr = 0; rr < 4; rr++) {
                const size_t row = (size_t)(b * 1024 + q0 + wave * 32 + g * 16 + quad * 4 + rr);
                O[row * 1024 + h * 64 + f * 16 + lml] = f2bf(of[g][f][rr] * inv[rr]);
            }
    }
}

// ---------------------------------------------------------------------------
extern "C" void kernel_launch(void* const* d_in, const int* in_sizes, int n_in,
                              void* d_out, int out_size, void* d_ws, size_t ws_size,
                              hipStream_t stream) {
    const float* q  = (const float*)d_in[0];
    const float* x  = (const float*)d_in[1];
    const float* Wq = (const float*)d_in[2];
    const float* bq = (const float*)d_in[3];
    const float* Wk = (const float*)d_in[4];
    const float* bk = (const float*)d_in[5];
    const float* Wv = (const float*)d_in[6];
    const float* bv = (const float*)d_in[7];
    const float* Wo = (const float*)d_in[8];
    const float* bo = (const float*)d_in[9];
    const int* adj  = (const int*)d_in[10];
    float* out = (float*)d_out;

    const size_t MB = 1024 * 1024;
    const size_t NELEM = (size_t)16 * MB;
    char* w = (char*)d_ws;

    dim3 gg(8, 128), tb(256);
    const size_t FULL_WS = 168 * MB + 128 * 1024;

    if (ws_size >= FULL_WS) {
        unsigned short* qb  = (unsigned short*)(w);
        unsigned short* xb  = (unsigned short*)(w + 32 * MB);
        unsigned short* Wqb = (unsigned short*)(w + 64 * MB);
        unsigned short* Wkb = (unsigned short*)(w + 66 * MB);
        unsigned short* Wvb = (unsigned short*)(w + 68 * MB);
        unsigned short* Wob = (unsigned short*)(w + 70 * MB);
        unsigned short* Qb  = (unsigned short*)(w + 72 * MB);
        unsigned short* Kb  = (unsigned short*)(w + 104 * MB);
        unsigned short* Vtb = (unsigned short*)(w + 136 * MB);
        unsigned* adjm      = (unsigned*)(w + 168 * MB);
        unsigned short* Ob  = qb;  // qb dead after Q-GEMM

        hipLaunchKernelGGL(cvt_bf16, dim3(8192), tb, 0, stream, q, qb, (int)(NELEM / 8));
        hipLaunchKernelGGL(cvt_bf16, dim3(8192), tb, 0, stream, x, xb, (int)(NELEM / 8));
        hipLaunchKernelGGL(cvt_w4, dim3(512, 4), tb, 0, stream, Wq, Wk, Wv, Wo,
                           Wqb, Wkb, Wvb, Wob);
        hipLaunchKernelGGL(pack_adj, dim3(128), tb, 0, stream, adj, adjm);

        hipLaunchKernelGGL((gemm_lds<0>), gg, tb, 0, stream, qb, Wqb, bq, (void*)Qb, QSCALE);
        hipLaunchKernelGGL((gemm_lds<0>), gg, tb, 0, stream, xb, Wkb, bk, (void*)Kb, 1.0f);
        hipLaunchKernelGGL((gemm_lds<2>), gg, tb, 0, stream, xb, Wvb, bv, (void*)Vtb, 1.0f);
        hipLaunchKernelGGL(attn_kernel, dim3(8, 16, 16), tb, 0, stream, Qb, Kb, Vtb, adjm, Ob);
        hipLaunchKernelGGL((gemm_lds<1>), gg, tb, 0, stream, Ob, Wob, bo, (void*)out, 1.0f);
    } else {
        // minimal path (134.1 MB): convert in GEMM staging
        unsigned short* Qb  = (unsigned short*)(w);
        unsigned short* Kb  = (unsigned short*)(w + 32 * MB);
        unsigned short* Vtb = (unsigned short*)(w + 64 * MB);
        unsigned short* Ob  = (unsigned short*)(w + 96 * MB);
        unsigned* adjm      = (unsigned*)(w + 128 * MB);

        hipLaunchKernelGGL(pack_adj, dim3(128), tb, 0, stream, adj, adjm);
        hipLaunchKernelGGL((gemm_bt<false, 0>), gg, tb, 0, stream,
                           (const void*)q, Wq, bq, (void*)Qb, QSCALE);
        hipLaunchKernelGGL((gemm_bt<false, 0>), gg, tb, 0, stream,
                           (const void*)x, Wk, bk, (void*)Kb, 1.0f);
        hipLaunchKernelGGL((gemm_bt<false, 2>), gg, tb, 0, stream,
                           (const void*)x, Wv, bv, (void*)Vtb, 1.0f);
        hipLaunchKernelGGL(attn_kernel, dim3(8, 16, 16), tb, 0, stream, Qb, Kb, Vtb, adjm, Ob);
        hipLaunchKernelGGL((gemm_bt<true, 1>), gg, tb, 0, stream,
                           (const void*)Ob, Wo, bo, (void*)out, 1.0f);
    }
}

// Round 2
// 480.858 us; speedup vs baseline: 1.1805x; 1.0859x over previous
//
#include <hip/hip_runtime.h>

// ---------------------------------------------------------------------------
// SelfAttentionDecoder: out = (softmax(mask((qWq^T+bq)(xWk^T+bk)^T/8)) (xWv^T+bv)) Wo^T + bo
// B=16, N1=N2=1024, D=1024, H=16, DH=16? no: H=16, DH=64.
// Round 6: XCD-aware swizzle (attn: 8 q-blocks of a (b,h) group on one XCD;
// GEMM: 8 n-blocks of an A row-panel on one XCD) + attn phase pipeline:
// K-frags -> QK(g0,g1) -> exp/store (per-g Ps double buffer) -> V-frags ->
// PV(g0,g1), setprio(1) around MFMA clusters, 2-shift mask unpack.
// ---------------------------------------------------------------------------

typedef float f32x4 __attribute__((ext_vector_type(4)));
typedef __bf16 bf16x8 __attribute__((ext_vector_type(8)));

// 0.125 * log2(e): QK^T scores arrive pre-scaled for exp2-based softmax.
#define QSCALE 0.18033688f

__device__ __forceinline__ unsigned short f2bf(float f) {
    unsigned u = __builtin_bit_cast(unsigned, f);
    unsigned r = u + 0x7fffu + ((u >> 16) & 1u);   // RNE
    return (unsigned short)(r >> 16);
}
__device__ __forceinline__ unsigned pk2(float a, float b) {
    return (unsigned)f2bf(a) | ((unsigned)f2bf(b) << 16);
}

// ---------------------------------------------------------------------------
// fp32 -> bf16 converters.
// ---------------------------------------------------------------------------
__global__ __launch_bounds__(256) void cvt_bf16(const float* __restrict__ src,
                                                unsigned short* __restrict__ dst,
                                                int n8) {
    const int idx = blockIdx.x * 256 + threadIdx.x;
    if (idx >= n8) return;
    float4 a = ((const float4*)src)[idx * 2];
    float4 b = ((const float4*)src)[idx * 2 + 1];
    uint4 u;
    u.x = pk2(a.x, a.y); u.y = pk2(a.z, a.w);
    u.z = pk2(b.x, b.y); u.w = pk2(b.z, b.w);
    ((uint4*)dst)[idx] = u;
}

__global__ __launch_bounds__(256) void cvt_w4(const float* __restrict__ W0,
                                              const float* __restrict__ W1,
                                              const float* __restrict__ W2,
                                              const float* __restrict__ W3,
                                              unsigned short* __restrict__ o0,
                                              unsigned short* __restrict__ o1,
                                              unsigned short* __restrict__ o2,
                                              unsigned short* __restrict__ o3) {
    const float* s = (blockIdx.y == 0) ? W0 : (blockIdx.y == 1) ? W1
                   : (blockIdx.y == 2) ? W2 : W3;
    unsigned short* d = (blockIdx.y == 0) ? o0 : (blockIdx.y == 1) ? o1
                      : (blockIdx.y == 2) ? o2 : o3;
    const int idx = blockIdx.x * 256 + threadIdx.x;   // 131072 chunks of 8
    float4 a = ((const float4*)s)[idx * 2];
    float4 b = ((const float4*)s)[idx * 2 + 1];
    uint4 u;
    u.x = pk2(a.x, a.y); u.y = pk2(a.z, a.w);
    u.z = pk2(b.x, b.y); u.w = pk2(b.z, b.w);
    ((uint4*)d)[idx] = u;
}

// ---------------------------------------------------------------------------
// GEMM (m97-class): C[M,N] = (A[M,K] @ W[N,K]^T + bias)*scale, bf16 in.
// M=16384 N=1024 K=1024. 128x128 tile, BK=64, 256 thr (4 waves, 2x2 of 64x64).
// Launched as 1D grid of 1024; XCD-aware swizzle: xcd = bid&7 owns 16
// consecutive A row-panels; the 8 n-blocks of a panel share that XCD's L2.
// Staging: 8x global_load_lds(16B)/thread/iter into unpadded 128x64 tiles;
// XOR swizzle on the GLOBAL source col-chunk (csrc = cpos ^ (row&7)).
// OUTM: 0 = bf16 row-major; 1 = fp32 row-major; 2 = bf16 V^T [b][h][dh][n2].
// ---------------------------------------------------------------------------
template <int OUTM>
__global__ __launch_bounds__(256) void gemm_lds(const unsigned short* __restrict__ A,
                                                const unsigned short* __restrict__ W,
                                                const float* __restrict__ bias,
                                                void* __restrict__ Cp,
                                                float scale) {
    constexpr int N = 1024, K = 1024;
    __shared__ unsigned short As[128 * 64];
    __shared__ unsigned short Bs[128 * 64];

    const int t    = threadIdx.x;
    const int wave = t >> 6;
    const int lane = t & 63;
    // XCD swizzle: bid&7 = XCD (round-robin dispatch); each XCD gets 16
    // consecutive row-panels, n-block fastest within the XCD's slice.
    const int bid  = blockIdx.x;
    const int xcd  = bid & 7;
    const int jj   = bid >> 3;                    // 0..127
    const int n0   = (jj & 7) * 128;
    const int m0   = (xcd * 16 + (jj >> 3)) * 128;
    const int wr   = (wave >> 1) * 64;
    const int wc   = (wave & 1) * 64;
    const int lm   = lane & 15;
    const int quad = lane >> 4;

    // staging: inst i covers LDS slots [(wave*4+i)*64 .. +64); slot s -> row
    // r=s>>3, chunk-pos p=s&7, source chunk csrc=p^(r&7).
    int aoff[4], boff[4];
#pragma unroll
    for (int i = 0; i < 4; i++) {
        const int slot = wave * 256 + i * 64 + lane;
        const int r = slot >> 3;
        const int csrc = (slot & 7) ^ (r & 7);
        aoff[i] = (m0 + r) * K + csrc * 8;
        boff[i] = (n0 + r) * K + csrc * 8;
    }

    f32x4 acc[4][4] = {};

    for (int k0 = 0; k0 < K; k0 += 64) {
#pragma unroll
        for (int i = 0; i < 4; i++) {
            __builtin_amdgcn_global_load_lds(
                (const __attribute__((address_space(1))) unsigned int*)(A + aoff[i] + k0),
                (__attribute__((address_space(3))) unsigned int*)((char*)As + wave * 4096 + i * 1024),
                16, 0, 0);
            __builtin_amdgcn_global_load_lds(
                (const __attribute__((address_space(1))) unsigned int*)(W + boff[i] + k0),
                (__attribute__((address_space(3))) unsigned int*)((char*)Bs + wave * 4096 + i * 1024),
                16, 0, 0);
        }
        __syncthreads();

        bf16x8 af[2][4], bfr[2][4];
#pragma unroll
        for (int ks = 0; ks < 2; ks++)
#pragma unroll
            for (int i = 0; i < 4; i++) {
                const int pos = ((ks * 4 + quad) ^ (lm & 7)) * 16;
                af[ks][i]  = *(const bf16x8*)((const char*)As + (wr + i * 16 + lm) * 128 + pos);
                bfr[ks][i] = *(const bf16x8*)((const char*)Bs + (wc + i * 16 + lm) * 128 + pos);
            }
#pragma unroll
        for (int ks = 0; ks < 2; ks++)
#pragma unroll
            for (int i = 0; i < 4; i++)
#pragma unroll
                for (int j = 0; j < 4; j++)
                    acc[i][j] = __builtin_amdgcn_mfma_f32_16x16x32_bf16(af[ks][i], bfr[ks][j],
                                                                        acc[i][j], 0, 0, 0);
        __syncthreads();
    }

    // ---- epilogue ----
#pragma unroll
    for (int i = 0; i < 4; i++) {
        const int row = m0 + wr + i * 16 + quad * 4;
#pragma unroll
        for (int j = 0; j < 4; j++) {
            const int col = n0 + wc + j * 16 + lm;
            const float bb = bias[col];
            if constexpr (OUTM == 2) {
                const int bi = row >> 10, n2 = row & 1023;
                const int hh = col >> 6, dh = col & 63;
                uint2 pkd;
                pkd.x = pk2((acc[i][j][0] + bb) * scale, (acc[i][j][1] + bb) * scale);
                pkd.y = pk2((acc[i][j][2] + bb) * scale, (acc[i][j][3] + bb) * scale);
                *(uint2*)&((unsigned short*)Cp)[((size_t)((bi * 16 + hh) * 64 + dh) << 10) + n2] = pkd;
            } else {
#pragma unroll
                for (int rr = 0; rr < 4; rr++) {
                    const float v = (acc[i][j][rr] + bb) * scale;
                    if constexpr (OUTM == 0)
                        ((unsigned short*)Cp)[(size_t)(row + rr) * N + col] = f2bf(v);
                    else
                        ((float*)Cp)[(size_t)(row + rr) * N + col] = v;
                }
            }
        }
    }
}

// ---------------------------------------------------------------------------
// Fallback GEMM (fp32 inputs, conversion in staging) — minimal-ws path only.
// ---------------------------------------------------------------------------
template <bool A_BF16, int OUTM>
__global__ __launch_bounds__(256) void gemm_bt(const void* __restrict__ Ap,
                                               const float* __restrict__ Wp,
                                               const float* __restrict__ bias,
                                               void* __restrict__ Cp,
                                               float scale) {
    constexpr int N = 1024, K = 1024;
    __shared__ unsigned short As[128 * 40];
    __shared__ unsigned short Bs[128 * 40];

    const int t    = threadIdx.x;
    const int n0   = blockIdx.x * 128;
    const int m0   = blockIdx.y * 128;
    const int wave = t >> 6;
    const int lane = t & 63;
    const int wr   = (wave >> 1) * 64;
    const int wc   = (wave & 1) * 64;
    const int lm   = lane & 15;
    const int quad = lane >> 4;
    const int kfr  = quad * 8;
    const int srow  = t >> 1;
    const int shalf = (t & 1) * 16;

    f32x4 acc[4][4] = {};

    for (int k0 = 0; k0 < K; k0 += 32) {
        {
            unsigned short* dst = &As[srow * 40 + shalf];
            if constexpr (A_BF16) {
                const unsigned short* pa =
                    (const unsigned short*)Ap + (size_t)(m0 + srow) * K + k0 + shalf;
                *(uint4*)dst       = *(const uint4*)pa;
                *(uint4*)(dst + 8) = *(const uint4*)(pa + 8);
            } else {
                const float* pa = (const float*)Ap + (size_t)(m0 + srow) * K + k0 + shalf;
                float4 f0 = *(const float4*)(pa + 0);
                float4 f1 = *(const float4*)(pa + 4);
                float4 f2 = *(const float4*)(pa + 8);
                float4 f3 = *(const float4*)(pa + 12);
                uint4 u0, u1;
                u0.x = pk2(f0.x, f0.y); u0.y = pk2(f0.z, f0.w);
                u0.z = pk2(f1.x, f1.y); u0.w = pk2(f1.z, f1.w);
                u1.x = pk2(f2.x, f2.y); u1.y = pk2(f2.z, f2.w);
                u1.z = pk2(f3.x, f3.y); u1.w = pk2(f3.z, f3.w);
                *(uint4*)dst       = u0;
                *(uint4*)(dst + 8) = u1;
            }
        }
        {
            const float* pb = Wp + (size_t)(n0 + srow) * K + k0 + shalf;
            float4 f0 = *(const float4*)(pb + 0);
            float4 f1 = *(const float4*)(pb + 4);
            float4 f2 = *(const float4*)(pb + 8);
            float4 f3 = *(const float4*)(pb + 12);
            uint4 u0, u1;
            u0.x = pk2(f0.x, f0.y); u0.y = pk2(f0.z, f0.w);
            u0.z = pk2(f1.x, f1.y); u0.w = pk2(f1.z, f1.w);
            u1.x = pk2(f2.x, f2.y); u1.y = pk2(f2.z, f2.w);
            u1.z = pk2(f3.x, f3.y); u1.w = pk2(f3.z, f3.w);
            unsigned short* dst = &Bs[srow * 40 + shalf];
            *(uint4*)dst       = u0;
            *(uint4*)(dst + 8) = u1;
        }
        __syncthreads();

        bf16x8 af[4], bfr[4];
#pragma unroll
        for (int i = 0; i < 4; i++)
            af[i] = *reinterpret_cast<const bf16x8*>(&As[(wr + i * 16 + lm) * 40 + kfr]);
#pragma unroll
        for (int j = 0; j < 4; j++)
            bfr[j] = *reinterpret_cast<const bf16x8*>(&Bs[(wc + j * 16 + lm) * 40 + kfr]);
#pragma unroll
        for (int i = 0; i < 4; i++)
#pragma unroll
            for (int j = 0; j < 4; j++)
                acc[i][j] = __builtin_amdgcn_mfma_f32_16x16x32_bf16(af[i], bfr[j],
                                                                    acc[i][j], 0, 0, 0);
        __syncthreads();
    }

#pragma unroll
    for (int i = 0; i < 4; i++) {
        const int row = m0 + wr + i * 16 + quad * 4;
#pragma unroll
        for (int j = 0; j < 4; j++) {
            const int col = n0 + wc + j * 16 + lm;
            const float bb = bias[col];
#pragma unroll
            for (int rr = 0; rr < 4; rr++) {
                const float v = (acc[i][j][rr] + bb) * scale;
                const int m = row + rr;
                if constexpr (OUTM == 0) {
                    ((unsigned short*)Cp)[(size_t)m * N + col] = f2bf(v);
                } else if constexpr (OUTM == 1) {
                    ((float*)Cp)[(size_t)m * N + col] = v;
                } else {
                    const int bi = m >> 10, n2 = m & 1023;
                    const int hh = col >> 6, dh = col & 63;
                    ((unsigned short*)Cp)[((size_t)((bi * 16 + hh) * 64 + dh) << 10) + n2] =
                        f2bf(v);
                }
            }
        }
    }
}

// ---------------------------------------------------------------------------
// Pack adj (int32 0/1, [1024][1024]) into bitmask [1024][32] words.
// ---------------------------------------------------------------------------
__global__ __launch_bounds__(256) void pack_adj(const int* __restrict__ adj,
                                                unsigned* __restrict__ adjm) {
    const int idx = blockIdx.x * 256 + threadIdx.x;  // 0..32767
    const int* src = adj + (size_t)idx * 32;
    unsigned w = 0;
#pragma unroll
    for (int i = 0; i < 32; i++) w |= (src[i] != 0 ? 1u : 0u) << i;
    adjm[idx] = w;
}

// ---------------------------------------------------------------------------
// MFMA flash attention, no-max softmax. 1D grid 2048, 4 waves.
// XCD swizzle: each XCD owns 32 (b,h) groups; the 8 q-blocks of a group run
// on ONE XCD so its K/V panel (256KB) is fetched once into that L2
// (concurrent working set ~3MB < 4MB).
// Per 64-kv chunk (phase pipeline):
//   mask uint2 loads -> STAGE(c+1, buf^1) -> K frags -> QK^T g0+g1 (setprio)
//   -> exp/mask/trunc-store to per-g Ps double buffer -> V frags
//   -> PV g0+g1 + l-mfma (setprio) -> one __syncthreads (vmcnt drain).
// LDS: 16K K + 16K V + 18K Ps = 50KB -> 3 blocks/CU.
// ---------------------------------------------------------------------------
__global__ __launch_bounds__(256, 3) void attn_kernel(const unsigned short* __restrict__ Q,
                                                      const unsigned short* __restrict__ K,
                                                      const unsigned short* __restrict__ Vt,
                                                      const unsigned* __restrict__ adjm,
                                                      unsigned short* __restrict__ O) {
    __shared__ unsigned short Kbuf[2][4096];     // [row=kv 0..63][pos 0..7 of 8 ushorts]
    __shared__ unsigned short Vbuf[2][4096];     // [row=dh 0..63][pos]
    __shared__ unsigned short Ps[4][2][16][72];  // per-wave, per-g P round-trip

    const int t    = threadIdx.x;
    const int wave = t >> 6;
    const int lane = t & 63;
    const int lml  = lane & 15;
    const int quad = lane >> 4;

    // XCD-aware decode: bid&7 = XCD; each XCD gets 32 consecutive (b,h)
    // groups, q-block fastest within the group.
    const int bid   = blockIdx.x;
    const int xcd   = bid & 7;
    const int jj    = bid >> 3;               // 0..255
    const int group = xcd * 32 + (jj >> 3);   // 0..255 = b*16+h
    const int q0    = (jj & 7) * 128;
    const int h     = group & 15;
    const int b     = group >> 4;

    // staging precompute: slot s covers buf bytes [s*16, s*16+16); row r=s>>3,
    // stored pos p=s&7, source chunk csrc=p^(r&7) (image: chunk c at c^(r&7)).
    int    ldofs[2];
    size_t kofs[2], vofs[2];
#pragma unroll
    for (int i = 0; i < 2; i++) {
        const int slot = i * 256 + t;
        const int r    = slot >> 3;
        const int cs   = (slot & 7) ^ (r & 7);
        ldofs[i] = slot * 16;
        kofs[i]  = (size_t)(b * 1024 + r) * 1024 + h * 64 + cs * 8;   // + j0*1024
        vofs[i]  = ((size_t)((b * 16 + h) * 64 + r) << 10) + cs * 8;  // + j0
    }

    bf16x8 aq[2][2];
#pragma unroll
    for (int g = 0; g < 2; g++) {
        const unsigned short* qp =
            Q + ((size_t)(b * 1024 + q0 + wave * 32 + g * 16 + lml) * 1024 + h * 64 + quad * 8);
        aq[g][0] = __builtin_bit_cast(bf16x8, *(const uint4*)qp);
        aq[g][1] = __builtin_bit_cast(bf16x8, *(const uint4*)(qp + 32));
    }

    bf16x8 bones;
    {
        const unsigned short o1 = (lml == 0) ? (unsigned short)0x3F80 : (unsigned short)0;
        const unsigned oo = (unsigned)o1 | ((unsigned)o1 << 16);
        uint4 u; u.x = oo; u.y = oo; u.z = oo; u.w = oo;
        bones = __builtin_bit_cast(bf16x8, u);
    }

    f32x4 of[2][4] = {};
    f32x4 ol[2] = {};

    auto STAGE = [&](int bi, int c) {
        const size_t j0 = (size_t)c * 64;
#pragma unroll
        for (int i = 0; i < 2; i++) {
            __builtin_amdgcn_global_load_lds(
                (const __attribute__((address_space(1))) unsigned int*)(K + kofs[i] + j0 * 1024),
                (__attribute__((address_space(3))) unsigned int*)((char*)&Kbuf[bi][0] + ldofs[i]),
                16, 0, 0);
            __builtin_amdgcn_global_load_lds(
                (const __attribute__((address_space(1))) unsigned int*)(Vt + vofs[i] + j0),
                (__attribute__((address_space(3))) unsigned int*)((char*)&Vbuf[bi][0] + ldofs[i]),
                16, 0, 0);
        }
    };

    STAGE(0, 0);
    __syncthreads();   // vmcnt(0) drain: buf0 ready

    int bi = 0;
    for (int c = 0; c < 16; ++c) {
        // mask words -> registers (issued before the stage so their wait
        // leaves the staging loads in flight)
        uint2 mw[2][4];
#pragma unroll
        for (int g = 0; g < 2; g++)
#pragma unroll
            for (int rr = 0; rr < 4; rr++) {
                const int row = q0 + wave * 32 + g * 16 + quad * 4 + rr;
                mw[g][rr] = *(const uint2*)&adjm[(size_t)row * 32 + c * 2];
            }

        if (c < 15) STAGE(bi ^ 1, c + 1);

        // --- phase 1: K frags + both QK^T passes ---
        bf16x8 bk[4][2];
#pragma unroll
        for (int f = 0; f < 4; f++)
#pragma unroll
            for (int ks = 0; ks < 2; ks++) {
                const int row = f * 16 + lml;
                const int pos = ((ks * 4 + quad) ^ (lml & 7)) * 16;
                bk[f][ks] = *(const bf16x8*)((const char*)&Kbuf[bi][0] + row * 128 + pos);
            }

        f32x4 sf[2][4] = {};
        __builtin_amdgcn_s_setprio(1);
#pragma unroll
        for (int g = 0; g < 2; g++)
#pragma unroll
            for (int f = 0; f < 4; f++)
#pragma unroll
                for (int ks = 0; ks < 2; ks++)
                    sf[g][f] = __builtin_amdgcn_mfma_f32_16x16x32_bf16(aq[g][ks], bk[f][ks],
                                                                       sf[g][f], 0, 0, 0);
        __builtin_amdgcn_s_setprio(0);

        // --- phase 2: softmax numerators into per-g Ps buffers ---
#pragma unroll
        for (int g = 0; g < 2; g++)
#pragma unroll
            for (int rr = 0; rr < 4; rr++) {
                const unsigned w0s = mw[g][rr].x >> lml;   // bit0 = f0, bit16 = f1
                const unsigned w1s = mw[g][rr].y >> lml;   // bit0 = f2, bit16 = f3
#pragma unroll
                for (int f = 0; f < 4; f++) {
                    const unsigned ws  = (f < 2) ? w0s : w1s;
                    const unsigned bit = (f & 1) ? ((ws >> 16) & 1u) : (ws & 1u);
                    // scores pre-scaled by log2e -> bare v_exp_f32 (=exp2)
                    const float p = bit ? __builtin_amdgcn_exp2f(sf[g][f][rr]) : 0.0f;
                    // truncating bf16 convert (bias cancels in O/l ratio)
                    Ps[wave][g][quad * 4 + rr][f * 16 + lml] =
                        (unsigned short)(__builtin_bit_cast(unsigned, p) >> 16);
                }
            }

        // --- phase 3: V frags (deferred: keeps peak VGPR below the 128 cliff) ---
        bf16x8 bv[4][2];
#pragma unroll
        for (int f = 0; f < 4; f++)
#pragma unroll
            for (int ks = 0; ks < 2; ks++) {
                const int row = f * 16 + lml;
                const int pos = ((ks * 4 + quad) ^ (lml & 7)) * 16;
                bv[f][ks] = *(const bf16x8*)((const char*)&Vbuf[bi][0] + row * 128 + pos);
            }

        // --- phase 4: both PV passes + row-sum mfma ---
#pragma unroll
        for (int g = 0; g < 2; g++) {
            const bf16x8 ap0 = *reinterpret_cast<const bf16x8*>(&Ps[wave][g][lml][quad * 8]);
            const bf16x8 ap1 = *reinterpret_cast<const bf16x8*>(&Ps[wave][g][lml][32 + quad * 8]);
            __builtin_amdgcn_s_setprio(1);
#pragma unroll
            for (int f = 0; f < 4; f++) {
                of[g][f] = __builtin_amdgcn_mfma_f32_16x16x32_bf16(ap0, bv[f][0], of[g][f], 0, 0, 0);
                of[g][f] = __builtin_amdgcn_mfma_f32_16x16x32_bf16(ap1, bv[f][1], of[g][f], 0, 0, 0);
            }
            ol[g] = __builtin_amdgcn_mfma_f32_16x16x32_bf16(ap0, bones, ol[g], 0, 0, 0);
            ol[g] = __builtin_amdgcn_mfma_f32_16x16x32_bf16(ap1, bones, ol[g], 0, 0, 0);
            __builtin_amdgcn_s_setprio(0);
        }

        __syncthreads();   // drain: next buf staged + all waves done reading bi
        bi ^= 1;
    }

#pragma unroll
    for (int g = 0; g < 2; g++) {
        float inv[4];
#pragma unroll
        for (int rr = 0; rr < 4; rr++)
            inv[rr] = 1.0f / __shfl(ol[g][rr], lane & 48);
#pragma unroll
        for (int f = 0; f < 4; f++)
#pragma unroll
            for (int rr = 0; rr < 4; rr++) {
                const size_t row = (size_t)(b * 1024 + q0 + wave * 32 + g * 16 + quad * 4 + rr);
                O[row * 1024 + h * 64 + f * 16 + lml] = f2bf(of[g][f][rr] * inv[rr]);
            }
    }
}

// ---------------------------------------------------------------------------
extern "C" void kernel_launch(void* const* d_in, const int* in_sizes, int n_in,
                              void* d_out, int out_size, void* d_ws, size_t ws_size,
                              hipStream_t stream) {
    const float* q  = (const float*)d_in[0];
    const float* x  = (const float*)d_in[1];
    const float* Wq = (const float*)d_in[2];
    const float* bq = (const float*)d_in[3];
    const float* Wk = (const float*)d_in[4];
    const float* bk = (const float*)d_in[5];
    const float* Wv = (const float*)d_in[6];
    const float* bv = (const float*)d_in[7];
    const float* Wo = (const float*)d_in[8];
    const float* bo = (const float*)d_in[9];
    const int* adj  = (const int*)d_in[10];
    float* out = (float*)d_out;

    const size_t MB = 1024 * 1024;
    const size_t NELEM = (size_t)16 * MB;
    char* w = (char*)d_ws;

    dim3 gswz(1024), tb(256);   // gemm_lds: 1D XCD-swizzled grid
    const size_t FULL_WS = 168 * MB + 128 * 1024;

    if (ws_size >= FULL_WS) {
        unsigned short* qb  = (unsigned short*)(w);
        unsigned short* xb  = (unsigned short*)(w + 32 * MB);
        unsigned short* Wqb = (unsigned short*)(w + 64 * MB);
        unsigned short* Wkb = (unsigned short*)(w + 66 * MB);
        unsigned short* Wvb = (unsigned short*)(w + 68 * MB);
        unsigned short* Wob = (unsigned short*)(w + 70 * MB);
        unsigned short* Qb  = (unsigned short*)(w + 72 * MB);
        unsigned short* Kb  = (unsigned short*)(w + 104 * MB);
        unsigned short* Vtb = (unsigned short*)(w + 136 * MB);
        unsigned* adjm      = (unsigned*)(w + 168 * MB);
        unsigned short* Ob  = qb;  // qb dead after Q-GEMM

        hipLaunchKernelGGL(cvt_bf16, dim3(8192), tb, 0, stream, q, qb, (int)(NELEM / 8));
        hipLaunchKernelGGL(cvt_bf16, dim3(8192), tb, 0, stream, x, xb, (int)(NELEM / 8));
        hipLaunchKernelGGL(cvt_w4, dim3(512, 4), tb, 0, stream, Wq, Wk, Wv, Wo,
                           Wqb, Wkb, Wvb, Wob);
        hipLaunchKernelGGL(pack_adj, dim3(128), tb, 0, stream, adj, adjm);

        hipLaunchKernelGGL((gemm_lds<0>), gswz, tb, 0, stream, qb, Wqb, bq, (void*)Qb, QSCALE);
        hipLaunchKernelGGL((gemm_lds<0>), gswz, tb, 0, stream, xb, Wkb, bk, (void*)Kb, 1.0f);
        hipLaunchKernelGGL((gemm_lds<2>), gswz, tb, 0, stream, xb, Wvb, bv, (void*)Vtb, 1.0f);
        hipLaunchKernelGGL(attn_kernel, dim3(2048), tb, 0, stream, Qb, Kb, Vtb, adjm, Ob);
        hipLaunchKernelGGL((gemm_lds<1>), gswz, tb, 0, stream, Ob, Wob, bo, (void*)out, 1.0f);
    } else {
        // minimal path (134.1 MB): convert in GEMM staging
        unsigned short* Qb  = (unsigned short*)(w);
        unsigned short* Kb  = (unsigned short*)(w + 32 * MB);
        unsigned short* Vtb = (unsigned short*)(w + 64 * MB);
        unsigned short* Ob  = (unsigned short*)(w + 96 * MB);
        unsigned* adjm      = (unsigned*)(w + 128 * MB);

        hipLaunchKernelGGL(pack_adj, dim3(128), tb, 0, stream, adj, adjm);
        hipLaunchKernelGGL((gemm_bt<false, 0>), dim3(8, 128), tb, 0, stream,
                           (const void*)q, Wq, bq, (void*)Qb, QSCALE);
        hipLaunchKernelGGL((gemm_bt<false, 0>), dim3(8, 128), tb, 0, stream,
                           (const void*)x, Wk, bk, (void*)Kb, 1.0f);
        hipLaunchKernelGGL((gemm_bt<false, 2>), dim3(8, 128), tb, 0, stream,
                           (const void*)x, Wv, bv, (void*)Vtb, 1.0f);
        hipLaunchKernelGGL(attn_kernel, dim3(2048), tb, 0, stream, Qb, Kb, Vtb, adjm, Ob);
        hipLaunchKernelGGL((gemm_bt<true, 1>), dim3(8, 128), tb, 0, stream,
                           (const void*)Ob, Wo, bo, (void*)out, 1.0f);
    }
}

// Round 3
// 474.912 us; speedup vs baseline: 1.1952x; 1.0125x over previous
//
#include <hip/hip_runtime.h>

// ---------------------------------------------------------------------------
// SelfAttentionDecoder: out = (softmax(mask((qWq^T+bq)(xWk^T+bk)^T/8)) (xWv^T+bv)) Wo^T + bo
// B=16, N1=N2=1024, D=1024, H=16, DH=64.
// Round 7: attn moves to 32x32x16 MFMA with swapped QK^T (A=K, B=Q) so the
// kv axis is lane-local; P->PV A-fragment built fully in registers via
// v_cvt_pk_bf16_f32 + v_permlane32_swap_b32 (T12). No Ps LDS round-trip.
// Row sums via all-ones B fragment (per-lane l[q], no shuffle at normalize).
// GEMMs/cvt unchanged from R6 (XCD-swizzled, gll-staged).
// ---------------------------------------------------------------------------

typedef float f32x4 __attribute__((ext_vector_type(4)));
typedef float f32x16 __attribute__((ext_vector_type(16)));
typedef __bf16 bf16x8 __attribute__((ext_vector_type(8)));

// 0.125 * log2(e): QK^T scores arrive pre-scaled for exp2-based softmax.
#define QSCALE 0.18033688f

__device__ __forceinline__ unsigned short f2bf(float f) {
    unsigned u = __builtin_bit_cast(unsigned, f);
    unsigned r = u + 0x7fffu + ((u >> 16) & 1u);   // RNE
    return (unsigned short)(r >> 16);
}
__device__ __forceinline__ unsigned pk2(float a, float b) {
    return (unsigned)f2bf(a) | ((unsigned)f2bf(b) << 16);
}

// ---------------------------------------------------------------------------
// fp32 -> bf16 converters.
// ---------------------------------------------------------------------------
__global__ __launch_bounds__(256) void cvt_bf16(const float* __restrict__ src,
                                                unsigned short* __restrict__ dst,
                                                int n8) {
    const int idx = blockIdx.x * 256 + threadIdx.x;
    if (idx >= n8) return;
    float4 a = ((const float4*)src)[idx * 2];
    float4 b = ((const float4*)src)[idx * 2 + 1];
    uint4 u;
    u.x = pk2(a.x, a.y); u.y = pk2(a.z, a.w);
    u.z = pk2(b.x, b.y); u.w = pk2(b.z, b.w);
    ((uint4*)dst)[idx] = u;
}

__global__ __launch_bounds__(256) void cvt_w4(const float* __restrict__ W0,
                                              const float* __restrict__ W1,
                                              const float* __restrict__ W2,
                                              const float* __restrict__ W3,
                                              unsigned short* __restrict__ o0,
                                              unsigned short* __restrict__ o1,
                                              unsigned short* __restrict__ o2,
                                              unsigned short* __restrict__ o3) {
    const float* s = (blockIdx.y == 0) ? W0 : (blockIdx.y == 1) ? W1
                   : (blockIdx.y == 2) ? W2 : W3;
    unsigned short* d = (blockIdx.y == 0) ? o0 : (blockIdx.y == 1) ? o1
                      : (blockIdx.y == 2) ? o2 : o3;
    const int idx = blockIdx.x * 256 + threadIdx.x;   // 131072 chunks of 8
    float4 a = ((const float4*)s)[idx * 2];
    float4 b = ((const float4*)s)[idx * 2 + 1];
    uint4 u;
    u.x = pk2(a.x, a.y); u.y = pk2(a.z, a.w);
    u.z = pk2(b.x, b.y); u.w = pk2(b.z, b.w);
    ((uint4*)d)[idx] = u;
}

// ---------------------------------------------------------------------------
// GEMM (m97-class): C[M,N] = (A[M,K] @ W[N,K]^T + bias)*scale, bf16 in.
// M=16384 N=1024 K=1024. 128x128 tile, BK=64, 256 thr (4 waves, 2x2 of 64x64).
// Launched as 1D grid of 1024; XCD-aware swizzle: xcd = bid&7 owns 16
// consecutive A row-panels; the 8 n-blocks of a panel share that XCD's L2.
// Staging: 8x global_load_lds(16B)/thread/iter into unpadded 128x64 tiles;
// XOR swizzle on the GLOBAL source col-chunk (csrc = cpos ^ (row&7)).
// OUTM: 0 = bf16 row-major; 1 = fp32 row-major; 2 = bf16 V^T [b][h][dh][n2].
// ---------------------------------------------------------------------------
template <int OUTM>
__global__ __launch_bounds__(256) void gemm_lds(const unsigned short* __restrict__ A,
                                                const unsigned short* __restrict__ W,
                                                const float* __restrict__ bias,
                                                void* __restrict__ Cp,
                                                float scale) {
    constexpr int N = 1024, K = 1024;
    __shared__ unsigned short As[128 * 64];
    __shared__ unsigned short Bs[128 * 64];

    const int t    = threadIdx.x;
    const int wave = t >> 6;
    const int lane = t & 63;
    const int bid  = blockIdx.x;
    const int xcd  = bid & 7;
    const int jj   = bid >> 3;                    // 0..127
    const int n0   = (jj & 7) * 128;
    const int m0   = (xcd * 16 + (jj >> 3)) * 128;
    const int wr   = (wave >> 1) * 64;
    const int wc   = (wave & 1) * 64;
    const int lm   = lane & 15;
    const int quad = lane >> 4;

    int aoff[4], boff[4];
#pragma unroll
    for (int i = 0; i < 4; i++) {
        const int slot = wave * 256 + i * 64 + lane;
        const int r = slot >> 3;
        const int csrc = (slot & 7) ^ (r & 7);
        aoff[i] = (m0 + r) * K + csrc * 8;
        boff[i] = (n0 + r) * K + csrc * 8;
    }

    f32x4 acc[4][4] = {};

    for (int k0 = 0; k0 < K; k0 += 64) {
#pragma unroll
        for (int i = 0; i < 4; i++) {
            __builtin_amdgcn_global_load_lds(
                (const __attribute__((address_space(1))) unsigned int*)(A + aoff[i] + k0),
                (__attribute__((address_space(3))) unsigned int*)((char*)As + wave * 4096 + i * 1024),
                16, 0, 0);
            __builtin_amdgcn_global_load_lds(
                (const __attribute__((address_space(1))) unsigned int*)(W + boff[i] + k0),
                (__attribute__((address_space(3))) unsigned int*)((char*)Bs + wave * 4096 + i * 1024),
                16, 0, 0);
        }
        __syncthreads();

        bf16x8 af[2][4], bfr[2][4];
#pragma unroll
        for (int ks = 0; ks < 2; ks++)
#pragma unroll
            for (int i = 0; i < 4; i++) {
                const int pos = ((ks * 4 + quad) ^ (lm & 7)) * 16;
                af[ks][i]  = *(const bf16x8*)((const char*)As + (wr + i * 16 + lm) * 128 + pos);
                bfr[ks][i] = *(const bf16x8*)((const char*)Bs + (wc + i * 16 + lm) * 128 + pos);
            }
#pragma unroll
        for (int ks = 0; ks < 2; ks++)
#pragma unroll
            for (int i = 0; i < 4; i++)
#pragma unroll
                for (int j = 0; j < 4; j++)
                    acc[i][j] = __builtin_amdgcn_mfma_f32_16x16x32_bf16(af[ks][i], bfr[ks][j],
                                                                        acc[i][j], 0, 0, 0);
        __syncthreads();
    }

    // ---- epilogue ----
#pragma unroll
    for (int i = 0; i < 4; i++) {
        const int row = m0 + wr + i * 16 + quad * 4;
#pragma unroll
        for (int j = 0; j < 4; j++) {
            const int col = n0 + wc + j * 16 + lm;
            const float bb = bias[col];
            if constexpr (OUTM == 2) {
                const int bi = row >> 10, n2 = row & 1023;
                const int hh = col >> 6, dh = col & 63;
                uint2 pkd;
                pkd.x = pk2((acc[i][j][0] + bb) * scale, (acc[i][j][1] + bb) * scale);
                pkd.y = pk2((acc[i][j][2] + bb) * scale, (acc[i][j][3] + bb) * scale);
                *(uint2*)&((unsigned short*)Cp)[((size_t)((bi * 16 + hh) * 64 + dh) << 10) + n2] = pkd;
            } else {
#pragma unroll
                for (int rr = 0; rr < 4; rr++) {
                    const float v = (acc[i][j][rr] + bb) * scale;
                    if constexpr (OUTM == 0)
                        ((unsigned short*)Cp)[(size_t)(row + rr) * N + col] = f2bf(v);
                    else
                        ((float*)Cp)[(size_t)(row + rr) * N + col] = v;
                }
            }
        }
    }
}

// ---------------------------------------------------------------------------
// Fallback GEMM (fp32 inputs, conversion in staging) — minimal-ws path only.
// ---------------------------------------------------------------------------
template <bool A_BF16, int OUTM>
__global__ __launch_bounds__(256) void gemm_bt(const void* __restrict__ Ap,
                                               const float* __restrict__ Wp,
                                               const float* __restrict__ bias,
                                               void* __restrict__ Cp,
                                               float scale) {
    constexpr int N = 1024, K = 1024;
    __shared__ unsigned short As[128 * 40];
    __shared__ unsigned short Bs[128 * 40];

    const int t    = threadIdx.x;
    const int n0   = blockIdx.x * 128;
    const int m0   = blockIdx.y * 128;
    const int wave = t >> 6;
    const int lane = t & 63;
    const int wr   = (wave >> 1) * 64;
    const int wc   = (wave & 1) * 64;
    const int lm   = lane & 15;
    const int quad = lane >> 4;
    const int kfr  = quad * 8;
    const int srow  = t >> 1;
    const int shalf = (t & 1) * 16;

    f32x4 acc[4][4] = {};

    for (int k0 = 0; k0 < K; k0 += 32) {
        {
            unsigned short* dst = &As[srow * 40 + shalf];
            if constexpr (A_BF16) {
                const unsigned short* pa =
                    (const unsigned short*)Ap + (size_t)(m0 + srow) * K + k0 + shalf;
                *(uint4*)dst       = *(const uint4*)pa;
                *(uint4*)(dst + 8) = *(const uint4*)(pa + 8);
            } else {
                const float* pa = (const float*)Ap + (size_t)(m0 + srow) * K + k0 + shalf;
                float4 f0 = *(const float4*)(pa + 0);
                float4 f1 = *(const float4*)(pa + 4);
                float4 f2 = *(const float4*)(pa + 8);
                float4 f3 = *(const float4*)(pa + 12);
                uint4 u0, u1;
                u0.x = pk2(f0.x, f0.y); u0.y = pk2(f0.z, f0.w);
                u0.z = pk2(f1.x, f1.y); u0.w = pk2(f1.z, f1.w);
                u1.x = pk2(f2.x, f2.y); u1.y = pk2(f2.z, f2.w);
                u1.z = pk2(f3.x, f3.y); u1.w = pk2(f3.z, f3.w);
                *(uint4*)dst       = u0;
                *(uint4*)(dst + 8) = u1;
            }
        }
        {
            const float* pb = Wp + (size_t)(n0 + srow) * K + k0 + shalf;
            float4 f0 = *(const float4*)(pb + 0);
            float4 f1 = *(const float4*)(pb + 4);
            float4 f2 = *(const float4*)(pb + 8);
            float4 f3 = *(const float4*)(pb + 12);
            uint4 u0, u1;
            u0.x = pk2(f0.x, f0.y); u0.y = pk2(f0.z, f0.w);
            u0.z = pk2(f1.x, f1.y); u0.w = pk2(f1.z, f1.w);
            u1.x = pk2(f2.x, f2.y); u1.y = pk2(f2.z, f2.w);
            u1.z = pk2(f3.x, f3.y); u1.w = pk2(f3.z, f3.w);
            unsigned short* dst = &Bs[srow * 40 + shalf];
            *(uint4*)dst       = u0;
            *(uint4*)(dst + 8) = u1;
        }
        __syncthreads();

        bf16x8 af[4], bfr[4];
#pragma unroll
        for (int i = 0; i < 4; i++)
            af[i] = *reinterpret_cast<const bf16x8*>(&As[(wr + i * 16 + lm) * 40 + kfr]);
#pragma unroll
        for (int j = 0; j < 4; j++)
            bfr[j] = *reinterpret_cast<const bf16x8*>(&Bs[(wc + j * 16 + lm) * 40 + kfr]);
#pragma unroll
        for (int i = 0; i < 4; i++)
#pragma unroll
            for (int j = 0; j < 4; j++)
                acc[i][j] = __builtin_amdgcn_mfma_f32_16x16x32_bf16(af[i], bfr[j],
                                                                    acc[i][j], 0, 0, 0);
        __syncthreads();
    }

#pragma unroll
    for (int i = 0; i < 4; i++) {
        const int row = m0 + wr + i * 16 + quad * 4;
#pragma unroll
        for (int j = 0; j < 4; j++) {
            const int col = n0 + wc + j * 16 + lm;
            const float bb = bias[col];
#pragma unroll
            for (int rr = 0; rr < 4; rr++) {
                const float v = (acc[i][j][rr] + bb) * scale;
                const int m = row + rr;
                if constexpr (OUTM == 0) {
                    ((unsigned short*)Cp)[(size_t)m * N + col] = f2bf(v);
                } else if constexpr (OUTM == 1) {
                    ((float*)Cp)[(size_t)m * N + col] = v;
                } else {
                    const int bi = m >> 10, n2 = m & 1023;
                    const int hh = col >> 6, dh = col & 63;
                    ((unsigned short*)Cp)[((size_t)((bi * 16 + hh) * 64 + dh) << 10) + n2] =
                        f2bf(v);
                }
            }
        }
    }
}

// ---------------------------------------------------------------------------
// Pack adj (int32 0/1, [1024][1024]) into bitmask [1024][32] words.
// ---------------------------------------------------------------------------
__global__ __launch_bounds__(256) void pack_adj(const int* __restrict__ adj,
                                                unsigned* __restrict__ adjm) {
    const int idx = blockIdx.x * 256 + threadIdx.x;  // 0..32767
    const int* src = adj + (size_t)idx * 32;
    unsigned w = 0;
#pragma unroll
    for (int i = 0; i < 32; i++) w |= (src[i] != 0 ? 1u : 0u) << i;
    adjm[idx] = w;
}

// ---------------------------------------------------------------------------
// MFMA flash attention, 32x32x16 shape, swapped QK^T, in-register softmax.
// 1D grid 2048 (XCD-swizzled), 4 waves x 32 q-rows = 128 q per block.
//
// Swapped QK^T: sf[f] = mfma32x32x16(A=K[f*32..+32][dh], B=Q) -> lane
// (q=l32, hi=l>>5) holds S[kv = f*32 + (r&3)+8*(r>>2)+4*hi][q] for r=0..15.
// Mask bit = (adjm word f) >> ((r&3)+8*(r>>2)+4*hi). p = exp2(sel).
// Pack: d[f][a][b] = cvt_pk(p[4a+2b], p[4a+2b+1]) = kv pair {8a+4hi+2b}.
// Redistribute: for s=2f+sg, b: permlane32_swap(d[f][2sg][b], d[f][2sg+1][b])
// -> A-frag dwords {b, b+2} of tA[s] (kv = s*16+hi*8+j), both halves correct.
// PV: of[e] += mfma(tA[s], Vfrag[e][s]); l: ol += mfma(tA[s], ones) -> every
// lane holds l[q] for its own rows (all-ones B) -> no shuffle at normalize.
// LDS: 2x8K K + 2x8K V = 32KB, double-buffered gll staging, 1 barrier/chunk.
// ---------------------------------------------------------------------------
__global__ __launch_bounds__(256, 3) void attn_kernel(const unsigned short* __restrict__ Q,
                                                      const unsigned short* __restrict__ K,
                                                      const unsigned short* __restrict__ Vt,
                                                      const unsigned* __restrict__ adjm,
                                                      unsigned short* __restrict__ O) {
    __shared__ unsigned short Kbuf[2][4096];   // [kv 0..63][8-chunk pos 0..7]
    __shared__ unsigned short Vbuf[2][4096];   // [dh 0..63][pos]

    const int t    = threadIdx.x;
    const int wave = t >> 6;
    const int lane = t & 63;
    const int l32  = lane & 31;
    const int hi   = lane >> 5;

    // XCD-aware decode: bid&7 = XCD; each XCD gets 32 consecutive (b,h)
    // groups, q-block fastest within the group.
    const int bid   = blockIdx.x;
    const int xcd   = bid & 7;
    const int jj    = bid >> 3;               // 0..255
    const int group = xcd * 32 + (jj >> 3);   // 0..255 = b*16+h
    const int q0    = (jj & 7) * 128;
    const int h     = group & 15;
    const int b     = group >> 4;

    const int qrow = q0 + wave * 32 + l32;    // this lane's q row

    // staging precompute: slot s covers buf bytes [s*16, s*16+16); row r=s>>3,
    // stored pos p=s&7, source chunk csrc=p^(r&7) (image: chunk c at c^(r&7)).
    int    ldofs[2];
    size_t kofs[2], vofs[2];
#pragma unroll
    for (int i = 0; i < 2; i++) {
        const int slot = i * 256 + t;
        const int r    = slot >> 3;
        const int cs   = (slot & 7) ^ (r & 7);
        ldofs[i] = slot * 16;
        kofs[i]  = (size_t)(b * 1024 + r) * 1024 + h * 64 + cs * 8;   // + j0*1024
        vofs[i]  = ((size_t)((b * 16 + h) * 64 + r) << 10) + cs * 8;  // + j0
    }

    // Q B-frags: aq[s] covers dh = s*16 + hi*8 .. +8 for col q = l32.
    bf16x8 aq[4];
    {
        const unsigned short* qp =
            Q + ((size_t)(b * 1024 + qrow) * 1024 + h * 64 + hi * 8);
#pragma unroll
        for (int s = 0; s < 4; s++)
            aq[s] = __builtin_bit_cast(bf16x8, *(const uint4*)(qp + s * 16));
    }

    bf16x8 bones;
    {
        uint4 u; u.x = 0x3F803F80u; u.y = u.x; u.z = u.x; u.w = u.x;
        bones = __builtin_bit_cast(bf16x8, u);   // all-ones B fragment
    }

    f32x16 of0 = {}, of1 = {}, ol = {};

    auto STAGE = [&](int bi, int c) {
        const size_t j0 = (size_t)c * 64;
#pragma unroll
        for (int i = 0; i < 2; i++) {
            __builtin_amdgcn_global_load_lds(
                (const __attribute__((address_space(1))) unsigned int*)(K + kofs[i] + j0 * 1024),
                (__attribute__((address_space(3))) unsigned int*)((char*)&Kbuf[bi][0] + ldofs[i]),
                16, 0, 0);
            __builtin_amdgcn_global_load_lds(
                (const __attribute__((address_space(1))) unsigned int*)(Vt + vofs[i] + j0),
                (__attribute__((address_space(3))) unsigned int*)((char*)&Vbuf[bi][0] + ldofs[i]),
                16, 0, 0);
        }
    };

    STAGE(0, 0);
    __syncthreads();   // vmcnt(0) drain: buf0 ready

    int bi = 0;
    for (int c = 0; c < 16; ++c) {
        // mask words -> registers (issued before the stage so their wait
        // leaves the staging loads in flight)
        const uint2 mw = *(const uint2*)&adjm[(size_t)qrow * 32 + c * 2];

        if (c < 15) STAGE(bi ^ 1, c + 1);

        // --- QK^T (swapped): sf[f] over dh steps ---
        f32x16 sf[2] = {{}, {}};
        __builtin_amdgcn_s_setprio(1);
#pragma unroll
        for (int f = 0; f < 2; f++)
#pragma unroll
            for (int s = 0; s < 4; s++) {
                const int pos = ((2 * s + hi) ^ (l32 & 7)) * 16;
                const bf16x8 kf =
                    *(const bf16x8*)((const char*)&Kbuf[bi][0] + (f * 32 + l32) * 128 + pos);
                sf[f] = __builtin_amdgcn_mfma_f32_32x32x16_bf16(kf, aq[s], sf[f], 0, 0, 0);
            }
        __builtin_amdgcn_s_setprio(0);

        // --- mask + exp2 + pack to bf16 pairs (in registers) ---
        unsigned d[2][4][2];
#pragma unroll
        for (int f = 0; f < 2; f++) {
            const unsigned wh = ((f == 0) ? mw.x : mw.y) >> (hi * 4);
            float p[16];
#pragma unroll
            for (int r = 0; r < 16; r++) {
                const unsigned bit = (wh >> ((r & 3) + 8 * (r >> 2))) & 1u;
                p[r] = __builtin_amdgcn_exp2f(bit ? sf[f][r] : -1e30f);
            }
#pragma unroll
            for (int a = 0; a < 4; a++)
#pragma unroll
                for (int bb = 0; bb < 2; bb++) {
                    unsigned dd;
                    asm("v_cvt_pk_bf16_f32 %0, %1, %2"
                        : "=v"(dd) : "v"(p[4 * a + 2 * bb]), "v"(p[4 * a + 2 * bb + 1]));
                    d[f][a][bb] = dd;
                }
        }

        // --- redistribute halves: build PV A-frags tA[s] (kv = s*16+hi*8+j) ---
        bf16x8 tA[4];
#pragma unroll
        for (int s = 0; s < 4; s++) {
            const int f = s >> 1, sg = s & 1;
            unsigned A0 = d[f][2 * sg][0], B0 = d[f][2 * sg + 1][0];
            unsigned A1 = d[f][2 * sg][1], B1 = d[f][2 * sg + 1][1];
            asm("v_permlane32_swap_b32 %0, %1" : "+v"(A0), "+v"(B0));
            asm("v_permlane32_swap_b32 %0, %1" : "+v"(A1), "+v"(B1));
            uint4 td; td.x = A0; td.y = A1; td.z = B0; td.w = B1;
            tA[s] = __builtin_bit_cast(bf16x8, td);
        }

        // --- PV + row-sum ---
        __builtin_amdgcn_s_setprio(1);
#pragma unroll
        for (int s = 0; s < 4; s++) {
            const int pos = ((2 * s + hi) ^ (l32 & 7)) * 16;
            const bf16x8 v0 = *(const bf16x8*)((const char*)&Vbuf[bi][0] + l32 * 128 + pos);
            const bf16x8 v1 = *(const bf16x8*)((const char*)&Vbuf[bi][0] + (32 + l32) * 128 + pos);
            of0 = __builtin_amdgcn_mfma_f32_32x32x16_bf16(tA[s], v0, of0, 0, 0, 0);
            of1 = __builtin_amdgcn_mfma_f32_32x32x16_bf16(tA[s], v1, of1, 0, 0, 0);
            ol  = __builtin_amdgcn_mfma_f32_32x32x16_bf16(tA[s], bones, ol, 0, 0, 0);
        }
        __builtin_amdgcn_s_setprio(0);

        __syncthreads();   // drain: next buf staged + all waves done reading bi
        bi ^= 1;
    }

    // --- normalize + store: lane holds q rows crow(r,hi), d = e*32 + l32 ---
#pragma unroll
    for (int r = 0; r < 16; r++) {
        const float iv = 1.0f / ol[r];
        const size_t row = (size_t)(b * 1024 + q0 + wave * 32 +
                                    (r & 3) + 8 * (r >> 2) + 4 * hi);
        unsigned short* op = O + row * 1024 + h * 64 + l32;
        op[0]  = f2bf(of0[r] * iv);
        op[32] = f2bf(of1[r] * iv);
    }
}

// ---------------------------------------------------------------------------
extern "C" void kernel_launch(void* const* d_in, const int* in_sizes, int n_in,
                              void* d_out, int out_size, void* d_ws, size_t ws_size,
                              hipStream_t stream) {
    const float* q  = (const float*)d_in[0];
    const float* x  = (const float*)d_in[1];
    const float* Wq = (const float*)d_in[2];
    const float* bq = (const float*)d_in[3];
    const float* Wk = (const float*)d_in[4];
    const float* bk = (const float*)d_in[5];
    const float* Wv = (const float*)d_in[6];
    const float* bv = (const float*)d_in[7];
    const float* Wo = (const float*)d_in[8];
    const float* bo = (const float*)d_in[9];
    const int* adj  = (const int*)d_in[10];
    float* out = (float*)d_out;

    const size_t MB = 1024 * 1024;
    const size_t NELEM = (size_t)16 * MB;
    char* w = (char*)d_ws;

    dim3 gswz(1024), tb(256);   // gemm_lds: 1D XCD-swizzled grid
    const size_t FULL_WS = 168 * MB + 128 * 1024;

    if (ws_size >= FULL_WS) {
        unsigned short* qb  = (unsigned short*)(w);
        unsigned short* xb  = (unsigned short*)(w + 32 * MB);
        unsigned short* Wqb = (unsigned short*)(w + 64 * MB);
        unsigned short* Wkb = (unsigned short*)(w + 66 * MB);
        unsigned short* Wvb = (unsigned short*)(w + 68 * MB);
        unsigned short* Wob = (unsigned short*)(w + 70 * MB);
        unsigned short* Qb  = (unsigned short*)(w + 72 * MB);
        unsigned short* Kb  = (unsigned short*)(w + 104 * MB);
        unsigned short* Vtb = (unsigned short*)(w + 136 * MB);
        unsigned* adjm      = (unsigned*)(w + 168 * MB);
        unsigned short* Ob  = qb;  // qb dead after Q-GEMM

        hipLaunchKernelGGL(cvt_bf16, dim3(8192), tb, 0, stream, q, qb, (int)(NELEM / 8));
        hipLaunchKernelGGL(cvt_bf16, dim3(8192), tb, 0, stream, x, xb, (int)(NELEM / 8));
        hipLaunchKernelGGL(cvt_w4, dim3(512, 4), tb, 0, stream, Wq, Wk, Wv, Wo,
                           Wqb, Wkb, Wvb, Wob);
        hipLaunchKernelGGL(pack_adj, dim3(128), tb, 0, stream, adj, adjm);

        hipLaunchKernelGGL((gemm_lds<0>), gswz, tb, 0, stream, qb, Wqb, bq, (void*)Qb, QSCALE);
        hipLaunchKernelGGL((gemm_lds<0>), gswz, tb, 0, stream, xb, Wkb, bk, (void*)Kb, 1.0f);
        hipLaunchKernelGGL((gemm_lds<2>), gswz, tb, 0, stream, xb, Wvb, bv, (void*)Vtb, 1.0f);
        hipLaunchKernelGGL(attn_kernel, dim3(2048), tb, 0, stream, Qb, Kb, Vtb, adjm, Ob);
        hipLaunchKernelGGL((gemm_lds<1>), gswz, tb, 0, stream, Ob, Wob, bo, (void*)out, 1.0f);
    } else {
        // minimal path (134.1 MB): convert in GEMM staging
        unsigned short* Qb  = (unsigned short*)(w);
        unsigned short* Kb  = (unsigned short*)(w + 32 * MB);
        unsigned short* Vtb = (unsigned short*)(w + 64 * MB);
        unsigned short* Ob  = (unsigned short*)(w + 96 * MB);
        unsigned* adjm      = (unsigned*)(w + 128 * MB);

        hipLaunchKernelGGL(pack_adj, dim3(128), tb, 0, stream, adj, adjm);
        hipLaunchKernelGGL((gemm_bt<false, 0>), dim3(8, 128), tb, 0, stream,
                           (const void*)q, Wq, bq, (void*)Qb, QSCALE);
        hipLaunchKernelGGL((gemm_bt<false, 0>), dim3(8, 128), tb, 0, stream,
                           (const void*)x, Wk, bk, (void*)Kb, 1.0f);
        hipLaunchKernelGGL((gemm_bt<false, 2>), dim3(8, 128), tb, 0, stream,
                           (const void*)x, Wv, bv, (void*)Vtb, 1.0f);
        hipLaunchKernelGGL(attn_kernel, dim3(2048), tb, 0, stream, Qb, Kb, Vtb, adjm, Ob);
        hipLaunchKernelGGL((gemm_bt<true, 1>), dim3(8, 128), tb, 0, stream,
                           (const void*)Ob, Wo, bo, (void*)out, 1.0f);
    }
}

// Round 4
// 448.902 us; speedup vs baseline: 1.2645x; 1.0579x over previous
//
#include <hip/hip_runtime.h>

// ---------------------------------------------------------------------------
// SelfAttentionDecoder: out = (softmax(mask((qWq^T+bq)(xWk^T+bk)^T/8)) (xWv^T+bv)) Wo^T + bo
// B=16, N1=N2=1024, D=1024, H=16, DH=64.
// Round 8: GEMM goes 2-phase double-buffered (T3 minimum recipe): prologue
// STAGE(buf0) -> loop { STAGE(buf^1, k+64); ds_read+MFMA on buf; barrier }.
// One barrier/iter; staging latency hides under compute. LDS 64KB, 2 blk/CU
// (grid 1024 = exactly 2 rounds, no tail). Attn unchanged except bank-phase
// pad (+16 ushorts) between K/V double-buffer halves. cvt_bf16 fused (y-dim).
// ---------------------------------------------------------------------------

typedef float f32x4 __attribute__((ext_vector_type(4)));
typedef float f32x16 __attribute__((ext_vector_type(16)));
typedef __bf16 bf16x8 __attribute__((ext_vector_type(8)));

// 0.125 * log2(e): QK^T scores arrive pre-scaled for exp2-based softmax.
#define QSCALE 0.18033688f

__device__ __forceinline__ unsigned short f2bf(float f) {
    unsigned u = __builtin_bit_cast(unsigned, f);
    unsigned r = u + 0x7fffu + ((u >> 16) & 1u);   // RNE
    return (unsigned short)(r >> 16);
}
__device__ __forceinline__ unsigned pk2(float a, float b) {
    return (unsigned)f2bf(a) | ((unsigned)f2bf(b) << 16);
}

// ---------------------------------------------------------------------------
// fp32 -> bf16 converters. cvt_bf16: y-dim selects (q, x) source.
// ---------------------------------------------------------------------------
__global__ __launch_bounds__(256) void cvt_bf16(const float* __restrict__ s0,
                                                unsigned short* __restrict__ d0,
                                                const float* __restrict__ s1,
                                                unsigned short* __restrict__ d1) {
    const float* src = blockIdx.y ? s1 : s0;
    unsigned short* dst = blockIdx.y ? d1 : d0;
    const int idx = blockIdx.x * 256 + threadIdx.x;
    float4 a = ((const float4*)src)[idx * 2];
    float4 b = ((const float4*)src)[idx * 2 + 1];
    uint4 u;
    u.x = pk2(a.x, a.y); u.y = pk2(a.z, a.w);
    u.z = pk2(b.x, b.y); u.w = pk2(b.z, b.w);
    ((uint4*)dst)[idx] = u;
}

__global__ __launch_bounds__(256) void cvt_w4(const float* __restrict__ W0,
                                              const float* __restrict__ W1,
                                              const float* __restrict__ W2,
                                              const float* __restrict__ W3,
                                              unsigned short* __restrict__ o0,
                                              unsigned short* __restrict__ o1,
                                              unsigned short* __restrict__ o2,
                                              unsigned short* __restrict__ o3) {
    const float* s = (blockIdx.y == 0) ? W0 : (blockIdx.y == 1) ? W1
                   : (blockIdx.y == 2) ? W2 : W3;
    unsigned short* d = (blockIdx.y == 0) ? o0 : (blockIdx.y == 1) ? o1
                      : (blockIdx.y == 2) ? o2 : o3;
    const int idx = blockIdx.x * 256 + threadIdx.x;   // 131072 chunks of 8
    float4 a = ((const float4*)s)[idx * 2];
    float4 b = ((const float4*)s)[idx * 2 + 1];
    uint4 u;
    u.x = pk2(a.x, a.y); u.y = pk2(a.z, a.w);
    u.z = pk2(b.x, b.y); u.w = pk2(b.z, b.w);
    ((uint4*)d)[idx] = u;
}

// ---------------------------------------------------------------------------
// GEMM (2-phase dbuf): C[M,N] = (A[M,K] @ W[N,K]^T + bias)*scale, bf16 in.
// M=16384 N=1024 K=1024. 128x128 tile, BK=64, 256 thr (4 waves, 2x2 of 64x64).
// 1D grid 1024, XCD swizzle: xcd=bid&7 owns 16 A row-panels (n fastest).
// K-loop: STAGE(buf^1, k+64) issued BEFORE compute on buf; single barrier
// per iter (its vmcnt(0) drain = stage completion). LDS 64KB -> 2 blk/CU,
// grid = exactly 2 occupancy rounds.
// Staging: 8x global_load_lds(16B)/thread into unpadded 128x64 tiles; XOR
// swizzle on the GLOBAL source chunk (csrc = cpos ^ (row&7)); frag reads at
// ((subk)^(row&7))*16 hit the 8-dword/bank b128 floor.
// OUTM: 0 = bf16 row-major; 1 = fp32 row-major; 2 = bf16 V^T [b][h][dh][n2].
// ---------------------------------------------------------------------------
template <int OUTM>
__global__ __launch_bounds__(256, 2) void gemm2(const unsigned short* __restrict__ A,
                                                const unsigned short* __restrict__ W,
                                                const float* __restrict__ bias,
                                                void* __restrict__ Cp,
                                                float scale) {
    constexpr int N = 1024, K = 1024;
    __shared__ unsigned short As[2][128 * 64];
    __shared__ unsigned short Bs[2][128 * 64];

    const int t    = threadIdx.x;
    const int wave = t >> 6;
    const int lane = t & 63;
    const int bid  = blockIdx.x;
    const int xcd  = bid & 7;
    const int jj   = bid >> 3;                    // 0..127
    const int n0   = (jj & 7) * 128;
    const int m0   = (xcd * 16 + (jj >> 3)) * 128;
    const int wr   = (wave >> 1) * 64;
    const int wc   = (wave & 1) * 64;
    const int lm   = lane & 15;
    const int quad = lane >> 4;

    int aoff[4], boff[4];
#pragma unroll
    for (int i = 0; i < 4; i++) {
        const int slot = wave * 256 + i * 64 + lane;
        const int r = slot >> 3;
        const int csrc = (slot & 7) ^ (r & 7);
        aoff[i] = (m0 + r) * K + csrc * 8;
        boff[i] = (n0 + r) * K + csrc * 8;
    }

    auto STAGE = [&](int cb, int k0) {
#pragma unroll
        for (int i = 0; i < 4; i++) {
            __builtin_amdgcn_global_load_lds(
                (const __attribute__((address_space(1))) unsigned int*)(A + aoff[i] + k0),
                (__attribute__((address_space(3))) unsigned int*)((char*)&As[cb][0] + wave * 4096 + i * 1024),
                16, 0, 0);
            __builtin_amdgcn_global_load_lds(
                (const __attribute__((address_space(1))) unsigned int*)(W + boff[i] + k0),
                (__attribute__((address_space(3))) unsigned int*)((char*)&Bs[cb][0] + wave * 4096 + i * 1024),
                16, 0, 0);
        }
    };

    f32x4 acc[4][4] = {};

    STAGE(0, 0);
    __syncthreads();   // vmcnt(0) drain: buf0 ready

    int cur = 0;
    for (int k0 = 0; k0 < K; k0 += 64) {
        if (k0 + 64 < K) STAGE(cur ^ 1, k0 + 64);   // prefetch next tile

        bf16x8 af[2][4], bfr[2][4];
#pragma unroll
        for (int ks = 0; ks < 2; ks++)
#pragma unroll
            for (int i = 0; i < 4; i++) {
                const int pos = ((ks * 4 + quad) ^ (lm & 7)) * 16;
                af[ks][i]  = *(const bf16x8*)((const char*)&As[cur][0] + (wr + i * 16 + lm) * 128 + pos);
                bfr[ks][i] = *(const bf16x8*)((const char*)&Bs[cur][0] + (wc + i * 16 + lm) * 128 + pos);
            }
#pragma unroll
        for (int ks = 0; ks < 2; ks++)
#pragma unroll
            for (int i = 0; i < 4; i++)
#pragma unroll
                for (int j = 0; j < 4; j++)
                    acc[i][j] = __builtin_amdgcn_mfma_f32_16x16x32_bf16(af[ks][i], bfr[ks][j],
                                                                        acc[i][j], 0, 0, 0);
        __syncthreads();   // all reads of buf done + next stage drained
        cur ^= 1;
    }

    // ---- epilogue ----
#pragma unroll
    for (int i = 0; i < 4; i++) {
        const int row = m0 + wr + i * 16 + quad * 4;
#pragma unroll
        for (int j = 0; j < 4; j++) {
            const int col = n0 + wc + j * 16 + lm;
            const float bb = bias[col];
            if constexpr (OUTM == 2) {
                const int bi = row >> 10, n2 = row & 1023;
                const int hh = col >> 6, dh = col & 63;
                uint2 pkd;
                pkd.x = pk2((acc[i][j][0] + bb) * scale, (acc[i][j][1] + bb) * scale);
                pkd.y = pk2((acc[i][j][2] + bb) * scale, (acc[i][j][3] + bb) * scale);
                *(uint2*)&((unsigned short*)Cp)[((size_t)((bi * 16 + hh) * 64 + dh) << 10) + n2] = pkd;
            } else {
#pragma unroll
                for (int rr = 0; rr < 4; rr++) {
                    const float v = (acc[i][j][rr] + bb) * scale;
                    if constexpr (OUTM == 0)
                        ((unsigned short*)Cp)[(size_t)(row + rr) * N + col] = f2bf(v);
                    else
                        ((float*)Cp)[(size_t)(row + rr) * N + col] = v;
                }
            }
        }
    }
}

// ---------------------------------------------------------------------------
// Fallback GEMM (fp32 inputs, conversion in staging) — minimal-ws path only.
// ---------------------------------------------------------------------------
template <bool A_BF16, int OUTM>
__global__ __launch_bounds__(256) void gemm_bt(const void* __restrict__ Ap,
                                               const float* __restrict__ Wp,
                                               const float* __restrict__ bias,
                                               void* __restrict__ Cp,
                                               float scale) {
    constexpr int N = 1024, K = 1024;
    __shared__ unsigned short As[128 * 40];
    __shared__ unsigned short Bs[128 * 40];

    const int t    = threadIdx.x;
    const int n0   = blockIdx.x * 128;
    const int m0   = blockIdx.y * 128;
    const int wave = t >> 6;
    const int lane = t & 63;
    const int wr   = (wave >> 1) * 64;
    const int wc   = (wave & 1) * 64;
    const int lm   = lane & 15;
    const int quad = lane >> 4;
    const int kfr  = quad * 8;
    const int srow  = t >> 1;
    const int shalf = (t & 1) * 16;

    f32x4 acc[4][4] = {};

    for (int k0 = 0; k0 < K; k0 += 32) {
        {
            unsigned short* dst = &As[srow * 40 + shalf];
            if constexpr (A_BF16) {
                const unsigned short* pa =
                    (const unsigned short*)Ap + (size_t)(m0 + srow) * K + k0 + shalf;
                *(uint4*)dst       = *(const uint4*)pa;
                *(uint4*)(dst + 8) = *(const uint4*)(pa + 8);
            } else {
                const float* pa = (const float*)Ap + (size_t)(m0 + srow) * K + k0 + shalf;
                float4 f0 = *(const float4*)(pa + 0);
                float4 f1 = *(const float4*)(pa + 4);
                float4 f2 = *(const float4*)(pa + 8);
                float4 f3 = *(const float4*)(pa + 12);
                uint4 u0, u1;
                u0.x = pk2(f0.x, f0.y); u0.y = pk2(f0.z, f0.w);
                u0.z = pk2(f1.x, f1.y); u0.w = pk2(f1.z, f1.w);
                u1.x = pk2(f2.x, f2.y); u1.y = pk2(f2.z, f2.w);
                u1.z = pk2(f3.x, f3.y); u1.w = pk2(f3.z, f3.w);
                *(uint4*)dst       = u0;
                *(uint4*)(dst + 8) = u1;
            }
        }
        {
            const float* pb = Wp + (size_t)(n0 + srow) * K + k0 + shalf;
            float4 f0 = *(const float4*)(pb + 0);
            float4 f1 = *(const float4*)(pb + 4);
            float4 f2 = *(const float4*)(pb + 8);
            float4 f3 = *(const float4*)(pb + 12);
            uint4 u0, u1;
            u0.x = pk2(f0.x, f0.y); u0.y = pk2(f0.z, f0.w);
            u0.z = pk2(f1.x, f1.y); u0.w = pk2(f1.z, f1.w);
            u1.x = pk2(f2.x, f2.y); u1.y = pk2(f2.z, f2.w);
            u1.z = pk2(f3.x, f3.y); u1.w = pk2(f3.z, f3.w);
            unsigned short* dst = &Bs[srow * 40 + shalf];
            *(uint4*)dst       = u0;
            *(uint4*)(dst + 8) = u1;
        }
        __syncthreads();

        bf16x8 af[4], bfr[4];
#pragma unroll
        for (int i = 0; i < 4; i++)
            af[i] = *reinterpret_cast<const bf16x8*>(&As[(wr + i * 16 + lm) * 40 + kfr]);
#pragma unroll
        for (int j = 0; j < 4; j++)
            bfr[j] = *reinterpret_cast<const bf16x8*>(&Bs[(wc + j * 16 + lm) * 40 + kfr]);
#pragma unroll
        for (int i = 0; i < 4; i++)
#pragma unroll
            for (int j = 0; j < 4; j++)
                acc[i][j] = __builtin_amdgcn_mfma_f32_16x16x32_bf16(af[i], bfr[j],
                                                                    acc[i][j], 0, 0, 0);
        __syncthreads();
    }

#pragma unroll
    for (int i = 0; i < 4; i++) {
        const int row = m0 + wr + i * 16 + quad * 4;
#pragma unroll
        for (int j = 0; j < 4; j++) {
            const int col = n0 + wc + j * 16 + lm;
            const float bb = bias[col];
#pragma unroll
            for (int rr = 0; rr < 4; rr++) {
                const float v = (acc[i][j][rr] + bb) * scale;
                const int m = row + rr;
                if constexpr (OUTM == 0) {
                    ((unsigned short*)Cp)[(size_t)m * N + col] = f2bf(v);
                } else if constexpr (OUTM == 1) {
                    ((float*)Cp)[(size_t)m * N + col] = v;
                } else {
                    const int bi = m >> 10, n2 = m & 1023;
                    const int hh = col >> 6, dh = col & 63;
                    ((unsigned short*)Cp)[((size_t)((bi * 16 + hh) * 64 + dh) << 10) + n2] =
                        f2bf(v);
                }
            }
        }
    }
}

// ---------------------------------------------------------------------------
// Pack adj (int32 0/1, [1024][1024]) into bitmask [1024][32] words.
// ---------------------------------------------------------------------------
__global__ __launch_bounds__(256) void pack_adj(const int* __restrict__ adj,
                                                unsigned* __restrict__ adjm) {
    const int idx = blockIdx.x * 256 + threadIdx.x;  // 0..32767
    const int* src = adj + (size_t)idx * 32;
    unsigned w = 0;
#pragma unroll
    for (int i = 0; i < 32; i++) w |= (src[i] != 0 ? 1u : 0u) << i;
    adjm[idx] = w;
}

// ---------------------------------------------------------------------------
// MFMA flash attention, 32x32x16 shape, swapped QK^T, in-register softmax.
// 1D grid 2048 (XCD-swizzled), 4 waves x 32 q-rows = 128 q per block.
// Double-buffer halves padded by 16 ushorts (32B = 8 banks) to decorrelate
// DMA-staging bank phase from concurrent frag reads on the other buffer.
// ---------------------------------------------------------------------------
__global__ __launch_bounds__(256, 3) void attn_kernel(const unsigned short* __restrict__ Q,
                                                      const unsigned short* __restrict__ K,
                                                      const unsigned short* __restrict__ Vt,
                                                      const unsigned* __restrict__ adjm,
                                                      unsigned short* __restrict__ O) {
    __shared__ unsigned short Kbuf[2][4112];   // [kv 0..63][8-chunk pos 0..7] (+16 pad)
    __shared__ unsigned short Vbuf[2][4112];   // [dh 0..63][pos] (+16 pad)

    const int t    = threadIdx.x;
    const int wave = t >> 6;
    const int lane = t & 63;
    const int l32  = lane & 31;
    const int hi   = lane >> 5;

    const int bid   = blockIdx.x;
    const int xcd   = bid & 7;
    const int jj    = bid >> 3;               // 0..255
    const int group = xcd * 32 + (jj >> 3);   // 0..255 = b*16+h
    const int q0    = (jj & 7) * 128;
    const int h     = group & 15;
    const int b     = group >> 4;

    const int qrow = q0 + wave * 32 + l32;    // this lane's q row

    int    ldofs[2];
    size_t kofs[2], vofs[2];
#pragma unroll
    for (int i = 0; i < 2; i++) {
        const int slot = i * 256 + t;
        const int r    = slot >> 3;
        const int cs   = (slot & 7) ^ (r & 7);
        ldofs[i] = slot * 16;
        kofs[i]  = (size_t)(b * 1024 + r) * 1024 + h * 64 + cs * 8;   // + j0*1024
        vofs[i]  = ((size_t)((b * 16 + h) * 64 + r) << 10) + cs * 8;  // + j0
    }

    // Q B-frags: aq[s] covers dh = s*16 + hi*8 .. +8 for col q = l32.
    bf16x8 aq[4];
    {
        const unsigned short* qp =
            Q + ((size_t)(b * 1024 + qrow) * 1024 + h * 64 + hi * 8);
#pragma unroll
        for (int s = 0; s < 4; s++)
            aq[s] = __builtin_bit_cast(bf16x8, *(const uint4*)(qp + s * 16));
    }

    bf16x8 bones;
    {
        uint4 u; u.x = 0x3F803F80u; u.y = u.x; u.z = u.x; u.w = u.x;
        bones = __builtin_bit_cast(bf16x8, u);   // all-ones B fragment
    }

    f32x16 of0 = {}, of1 = {}, ol = {};

    auto STAGE = [&](int bi, int c) {
        const size_t j0 = (size_t)c * 64;
#pragma unroll
        for (int i = 0; i < 2; i++) {
            __builtin_amdgcn_global_load_lds(
                (const __attribute__((address_space(1))) unsigned int*)(K + kofs[i] + j0 * 1024),
                (__attribute__((address_space(3))) unsigned int*)((char*)&Kbuf[bi][0] + ldofs[i]),
                16, 0, 0);
            __builtin_amdgcn_global_load_lds(
                (const __attribute__((address_space(1))) unsigned int*)(Vt + vofs[i] + j0),
                (__attribute__((address_space(3))) unsigned int*)((char*)&Vbuf[bi][0] + ldofs[i]),
                16, 0, 0);
        }
    };

    STAGE(0, 0);
    __syncthreads();   // vmcnt(0) drain: buf0 ready

    int bi = 0;
    for (int c = 0; c < 16; ++c) {
        const uint2 mw = *(const uint2*)&adjm[(size_t)qrow * 32 + c * 2];

        if (c < 15) STAGE(bi ^ 1, c + 1);

        // --- QK^T (swapped): sf[f] over dh steps ---
        f32x16 sf[2] = {{}, {}};
        __builtin_amdgcn_s_setprio(1);
#pragma unroll
        for (int f = 0; f < 2; f++)
#pragma unroll
            for (int s = 0; s < 4; s++) {
                const int pos = ((2 * s + hi) ^ (l32 & 7)) * 16;
                const bf16x8 kf =
                    *(const bf16x8*)((const char*)&Kbuf[bi][0] + (f * 32 + l32) * 128 + pos);
                sf[f] = __builtin_amdgcn_mfma_f32_32x32x16_bf16(kf, aq[s], sf[f], 0, 0, 0);
            }
        __builtin_amdgcn_s_setprio(0);

        // --- mask + exp2 + pack to bf16 pairs (in registers) ---
        unsigned d[2][4][2];
#pragma unroll
        for (int f = 0; f < 2; f++) {
            const unsigned wh = ((f == 0) ? mw.x : mw.y) >> (hi * 4);
            float p[16];
#pragma unroll
            for (int r = 0; r < 16; r++) {
                const unsigned bit = (wh >> ((r & 3) + 8 * (r >> 2))) & 1u;
                p[r] = __builtin_amdgcn_exp2f(bit ? sf[f][r] : -1e30f);
            }
#pragma unroll
            for (int a = 0; a < 4; a++)
#pragma unroll
                for (int bb = 0; bb < 2; bb++) {
                    unsigned dd;
                    asm("v_cvt_pk_bf16_f32 %0, %1, %2"
                        : "=v"(dd) : "v"(p[4 * a + 2 * bb]), "v"(p[4 * a + 2 * bb + 1]));
                    d[f][a][bb] = dd;
                }
        }

        // --- redistribute halves: build PV A-frags tA[s] (kv = s*16+hi*8+j) ---
        bf16x8 tA[4];
#pragma unroll
        for (int s = 0; s < 4; s++) {
            const int f = s >> 1, sg = s & 1;
            unsigned A0 = d[f][2 * sg][0], B0 = d[f][2 * sg + 1][0];
            unsigned A1 = d[f][2 * sg][1], B1 = d[f][2 * sg + 1][1];
            asm("v_permlane32_swap_b32 %0, %1" : "+v"(A0), "+v"(B0));
            asm("v_permlane32_swap_b32 %0, %1" : "+v"(A1), "+v"(B1));
            uint4 td; td.x = A0; td.y = A1; td.z = B0; td.w = B1;
            tA[s] = __builtin_bit_cast(bf16x8, td);
        }

        // --- PV + row-sum ---
        __builtin_amdgcn_s_setprio(1);
#pragma unroll
        for (int s = 0; s < 4; s++) {
            const int pos = ((2 * s + hi) ^ (l32 & 7)) * 16;
            const bf16x8 v0 = *(const bf16x8*)((const char*)&Vbuf[bi][0] + l32 * 128 + pos);
            const bf16x8 v1 = *(const bf16x8*)((const char*)&Vbuf[bi][0] + (32 + l32) * 128 + pos);
            of0 = __builtin_amdgcn_mfma_f32_32x32x16_bf16(tA[s], v0, of0, 0, 0, 0);
            of1 = __builtin_amdgcn_mfma_f32_32x32x16_bf16(tA[s], v1, of1, 0, 0, 0);
            ol  = __builtin_amdgcn_mfma_f32_32x32x16_bf16(tA[s], bones, ol, 0, 0, 0);
        }
        __builtin_amdgcn_s_setprio(0);

        __syncthreads();   // drain: next buf staged + all waves done reading bi
        bi ^= 1;
    }

    // --- normalize + store: lane holds q rows crow(r,hi), d = e*32 + l32 ---
#pragma unroll
    for (int r = 0; r < 16; r++) {
        const float iv = 1.0f / ol[r];
        const size_t row = (size_t)(b * 1024 + q0 + wave * 32 +
                                    (r & 3) + 8 * (r >> 2) + 4 * hi);
        unsigned short* op = O + row * 1024 + h * 64 + l32;
        op[0]  = f2bf(of0[r] * iv);
        op[32] = f2bf(of1[r] * iv);
    }
}

// ---------------------------------------------------------------------------
extern "C" void kernel_launch(void* const* d_in, const int* in_sizes, int n_in,
                              void* d_out, int out_size, void* d_ws, size_t ws_size,
                              hipStream_t stream) {
    const float* q  = (const float*)d_in[0];
    const float* x  = (const float*)d_in[1];
    const float* Wq = (const float*)d_in[2];
    const float* bq = (const float*)d_in[3];
    const float* Wk = (const float*)d_in[4];
    const float* bk = (const float*)d_in[5];
    const float* Wv = (const float*)d_in[6];
    const float* bv = (const float*)d_in[7];
    const float* Wo = (const float*)d_in[8];
    const float* bo = (const float*)d_in[9];
    const int* adj  = (const int*)d_in[10];
    float* out = (float*)d_out;

    const size_t MB = 1024 * 1024;
    char* w = (char*)d_ws;

    dim3 gswz(1024), tb(256);   // gemm2: 1D XCD-swizzled grid
    const size_t FULL_WS = 168 * MB + 128 * 1024;

    if (ws_size >= FULL_WS) {
        unsigned short* qb  = (unsigned short*)(w);
        unsigned short* xb  = (unsigned short*)(w + 32 * MB);
        unsigned short* Wqb = (unsigned short*)(w + 64 * MB);
        unsigned short* Wkb = (unsigned short*)(w + 66 * MB);
        unsigned short* Wvb = (unsigned short*)(w + 68 * MB);
        unsigned short* Wob = (unsigned short*)(w + 70 * MB);
        unsigned short* Qb  = (unsigned short*)(w + 72 * MB);
        unsigned short* Kb  = (unsigned short*)(w + 104 * MB);
        unsigned short* Vtb = (unsigned short*)(w + 136 * MB);
        unsigned* adjm      = (unsigned*)(w + 168 * MB);
        unsigned short* Ob  = qb;  // qb dead after Q-GEMM

        hipLaunchKernelGGL(cvt_bf16, dim3(8192, 2), tb, 0, stream, q, qb, x, xb);
        hipLaunchKernelGGL(cvt_w4, dim3(512, 4), tb, 0, stream, Wq, Wk, Wv, Wo,
                           Wqb, Wkb, Wvb, Wob);
        hipLaunchKernelGGL(pack_adj, dim3(128), tb, 0, stream, adj, adjm);

        hipLaunchKernelGGL((gemm2<0>), gswz, tb, 0, stream, qb, Wqb, bq, (void*)Qb, QSCALE);
        hipLaunchKernelGGL((gemm2<0>), gswz, tb, 0, stream, xb, Wkb, bk, (void*)Kb, 1.0f);
        hipLaunchKernelGGL((gemm2<2>), gswz, tb, 0, stream, xb, Wvb, bv, (void*)Vtb, 1.0f);
        hipLaunchKernelGGL(attn_kernel, dim3(2048), tb, 0, stream, Qb, Kb, Vtb, adjm, Ob);
        hipLaunchKernelGGL((gemm2<1>), gswz, tb, 0, stream, Ob, Wob, bo, (void*)out, 1.0f);
    } else {
        // minimal path (134.1 MB): convert in GEMM staging
        unsigned short* Qb  = (unsigned short*)(w);
        unsigned short* Kb  = (unsigned short*)(w + 32 * MB);
        unsigned short* Vtb = (unsigned short*)(w + 64 * MB);
        unsigned short* Ob  = (unsigned short*)(w + 96 * MB);
        unsigned* adjm      = (unsigned*)(w + 128 * MB);

        hipLaunchKernelGGL(pack_adj, dim3(128), tb, 0, stream, adj, adjm);
        hipLaunchKernelGGL((gemm_bt<false, 0>), dim3(8, 128), tb, 0, stream,
                           (const void*)q, Wq, bq, (void*)Qb, QSCALE);
        hipLaunchKernelGGL((gemm_bt<false, 0>), dim3(8, 128), tb, 0, stream,
                           (const void*)x, Wk, bk, (void*)Kb, 1.0f);
        hipLaunchKernelGGL((gemm_bt<false, 2>), dim3(8, 128), tb, 0, stream,
                           (const void*)x, Wv, bv, (void*)Vtb, 1.0f);
        hipLaunchKernelGGL(attn_kernel, dim3(2048), tb, 0, stream, Qb, Kb, Vtb, adjm, Ob);
        hipLaunchKernelGGL((gemm_bt<true, 1>), dim3(8, 128), tb, 0, stream,
                           (const void*)Ob, Wo, bo, (void*)out, 1.0f);
    }
}